// Round 3
// baseline (877.511 us; speedup 1.0000x reference)
//
#include <hip/hip_runtime.h>

namespace {

constexpr int BB = 2048;   // batch
constexpr int TT = 256;    // time steps

typedef __attribute__((ext_vector_type(8))) short bf8;          // 8 bf16 (4 VGPR)
typedef __attribute__((ext_vector_type(4))) float f4;           // MFMA acc
typedef __attribute__((ext_vector_type(4))) unsigned short us4;

#define MFMA16(a, b, c) __builtin_amdgcn_mfma_f32_16x16x32_bf16((a), (b), (c), 0, 0, 0)

__device__ __forceinline__ float sigm(float x) {
  return __builtin_amdgcn_rcpf(1.f + __expf(-x));
}
__device__ __forceinline__ float tanh_f(float x) {
  float e = __expf(2.f * x);
  return 1.f - 2.f * __builtin_amdgcn_rcpf(e + 1.f);
}
__device__ __forceinline__ void mk_hilo(float v, short& hi, short& lo) {
  unsigned int u = __float_as_uint(v);
  hi = (short)(u >> 16);
  float r = v - __uint_as_float(u & 0xffff0000u);
  lo = (short)(__float_as_uint(r) >> 16);
}

// ============ all 4 GRU layers, layer-pipelined in one block ============
// Block = 1024 threads = 16 waves = 4 groups of 4 waves. Group g = layer g,
// processing its timestep t = slot - g. Inter-layer y and per-layer h state
// live in LDS, parity double-buffered; ONE barrier per slot.
__global__ __launch_bounds__(1024) void gru_all(
    const float* __restrict__ xs, const float* __restrict__ xp,
    const float* __restrict__ W0s, const float* __restrict__ W0p,
    const float* __restrict__ Wihs, const float* __restrict__ Wihp,  // [3][192][64]
    const float* __restrict__ Whhs, const float* __restrict__ Whhp,  // [4][192][64]
    const float* __restrict__ bihs, const float* __restrict__ bihp,  // [4][192]
    const float* __restrict__ bhhs, const float* __restrict__ bhhp,
    float* __restrict__ hlast) {
  const int tid = threadIdx.x;
  const int Wv = tid >> 6, lane = tid & 63;
  const int g = Wv >> 2, w = Wv & 3;      // layer group, wave-in-group
  const int n15 = lane & 15, q = lane >> 4;
  const int blk = blockIdx.x, stack = blk >> 7;
  const int b0 = (blk & 127) * 16;
  const int in_dim = stack ? 4 : 1;

  const float* Wh = (stack ? Whhp : Whhs) + (size_t)g * 192 * 64;
  const float* bi = (stack ? bihp : bihs) + g * 192;
  const float* bh = (stack ? bhhp : bhhs) + g * 192;
  const float* Wx = (g >= 1) ? ((stack ? Wihp : Wihs) + (size_t)(g - 1) * 192 * 64)
                             : nullptr;

  // LDS: per-layer h (hi/lo), inter-layer y, layer-0 input weights.
  __shared__ unsigned short hbuf[4][2][2][16][72];  // [g][parity][hi/lo][n][64+8]
  __shared__ unsigned short ybuf[3][2][16][72];     // [g][parity][n][64+8]
  __shared__ float w0T[4][192];                     // layer-0 Wih transposed

  // ---- one-time: weight fragments into registers ----
  // A-frag: row = lane&15, k = (lane>>4)*8 + j. Wave w owns Mtiles {w,w+4,w+8}.
  bf8 whh_[3][2], whl_[3][2], wxh_[3][2];
  const int mrow = 16 * w + n15;
  #pragma unroll
  for (int i = 0; i < 3; ++i) {
    #pragma unroll
    for (int kt = 0; kt < 2; ++kt) {
      const float* ph_ = Wh + (size_t)(i * 64 + mrow) * 64 + kt * 32 + q * 8;
      f4 ha = *(const f4*)ph_, hc = *(const f4*)(ph_ + 4);
      bf8 h2, l2;
      #pragma unroll
      for (int j = 0; j < 8; ++j) {
        float vh = (j < 4) ? ha[j] : hc[j - 4];
        short a_, b_;
        mk_hilo(vh, a_, b_); h2[j] = a_; l2[j] = b_;
      }
      whh_[i][kt] = h2; whl_[i][kt] = l2;
      if (g >= 1) {
        const float* px_ = Wx + (size_t)(i * 64 + mrow) * 64 + kt * 32 + q * 8;
        f4 xa = *(const f4*)px_, xc = *(const f4*)(px_ + 4);
        bf8 h1;
        #pragma unroll
        for (int j = 0; j < 8; ++j) {
          float vx = (j < 4) ? xa[j] : xc[j - 4];
          h1[j] = (short)(__float_as_uint(vx) >> 16);  // hi only (x is exact bf16)
        }
        wxh_[i][kt] = h1;
      }
    }
  }
  // layer-0 input weights -> LDS (transposed [d][192])
  if (tid < 4 * 192) {
    int d = tid / 192, j = tid - d * 192;
    w0T[d][j] = (d < in_dim) ? (stack ? W0p[j * 4 + d] : W0s[j]) : 0.f;
  }
  // zero h parity buffers
  for (int e = tid; e < 4 * 2 * 2 * 16 * 72; e += 1024)
    ((unsigned short*)hbuf)[e] = 0;

  const int mu = 16 * w + 4 * q;  // C layout: this lane's 4 units mu..mu+3, batch n15
  f4 bR, bZ, bNx, bNh;
  #pragma unroll
  for (int r = 0; r < 4; ++r) {
    bR[r]  = bi[mu + r] + bh[mu + r];
    bZ[r]  = bi[64 + mu + r] + bh[64 + mu + r];
    bNx[r] = bi[128 + mu + r];
    bNh[r] = bh[128 + mu + r];
  }

  f4 h = {0.f, 0.f, 0.f, 0.f};
  // group-0 global x prefetch (one value set per lane: batch row b0+n15)
  const size_t xrow = (size_t)(b0 + n15);
  float px[4] = {0.f, 0.f, 0.f, 0.f};
  if (g == 0) {
    if (stack) { f4 t4 = *(const f4*)(xp + xrow * TT * 4); px[0]=t4[0]; px[1]=t4[1]; px[2]=t4[2]; px[3]=t4[3]; }
    else       { px[0] = xs[xrow * TT]; }
  }
  __syncthreads();

  #pragma unroll 1
  for (int s = 0; s < TT + 3; ++s) {
    const int t = s - g;
    if (t >= 0 && t < TT) {
      const int p = t & 1;
      // h B-frags (hi and lo)
      bf8 hh0 = *(const bf8*)&hbuf[g][p][0][n15][q * 8];
      bf8 hh1 = *(const bf8*)&hbuf[g][p][0][n15][32 + q * 8];
      bf8 hl0 = *(const bf8*)&hbuf[g][p][1][n15][q * 8];
      bf8 hl1 = *(const bf8*)&hbuf[g][p][1][n15][32 + q * 8];

      f4 aR = bR, aZ = bZ, aNx = bNx, aNh = bNh;

      if (g == 0) {
        // x-projection via VALU (K = 1 or 4), weights from LDS
        #pragma unroll 1
        for (int d = 0; d < in_dim; ++d) {
          f4 wr = *(const f4*)&w0T[d][mu];
          f4 wz = *(const f4*)&w0T[d][64 + mu];
          f4 wn = *(const f4*)&w0T[d][128 + mu];
          float xv = px[d];
          #pragma unroll
          for (int r = 0; r < 4; ++r) {
            aR[r]  = fmaf(wr[r], xv, aR[r]);
            aZ[r]  = fmaf(wz[r], xv, aZ[r]);
            aNx[r] = fmaf(wn[r], xv, aNx[r]);
          }
        }
        // prefetch next timestep's x
        if (t + 1 < TT) {
          if (stack) { f4 t4 = *(const f4*)(xp + (xrow * TT + t + 1) * 4); px[0]=t4[0]; px[1]=t4[1]; px[2]=t4[2]; px[3]=t4[3]; }
          else       { px[0] = xs[xrow * TT + t + 1]; }
        }
      } else {
        // x B-frags from previous layer's y (written last slot)
        bf8 xc0 = *(const bf8*)&ybuf[g - 1][p][n15][q * 8];
        bf8 xc1 = *(const bf8*)&ybuf[g - 1][p][n15][32 + q * 8];
        aR  = MFMA16(wxh_[0][0], xc0, aR);  aR  = MFMA16(wxh_[0][1], xc1, aR);
        aZ  = MFMA16(wxh_[1][0], xc0, aZ);  aZ  = MFMA16(wxh_[1][1], xc1, aZ);
        aNx = MFMA16(wxh_[2][0], xc0, aNx); aNx = MFMA16(wxh_[2][1], xc1, aNx);
      }
      // h-part: Wh_hi@h_hi + Wh_lo@h_hi + Wh_hi@h_lo
      aR  = MFMA16(whh_[0][0], hh0, aR);  aR  = MFMA16(whh_[0][1], hh1, aR);
      aZ  = MFMA16(whh_[1][0], hh0, aZ);  aZ  = MFMA16(whh_[1][1], hh1, aZ);
      aNh = MFMA16(whh_[2][0], hh0, aNh); aNh = MFMA16(whh_[2][1], hh1, aNh);
      aR  = MFMA16(whl_[0][0], hh0, aR);  aR  = MFMA16(whl_[0][1], hh1, aR);
      aZ  = MFMA16(whl_[1][0], hh0, aZ);  aZ  = MFMA16(whl_[1][1], hh1, aZ);
      aNh = MFMA16(whl_[2][0], hh0, aNh); aNh = MFMA16(whl_[2][1], hh1, aNh);
      aR  = MFMA16(whh_[0][0], hl0, aR);  aR  = MFMA16(whh_[0][1], hl1, aR);
      aZ  = MFMA16(whh_[1][0], hl0, aZ);  aZ  = MFMA16(whh_[1][1], hl1, aZ);
      aNh = MFMA16(whh_[2][0], hl0, aNh); aNh = MFMA16(whh_[2][1], hl1, aNh);

      #pragma unroll
      for (int r = 0; r < 4; ++r) {
        float rr = sigm(aR[r]);
        float zz = sigm(aZ[r]);
        float nn = tanh_f(aNx[r] + rr * aNh[r]);
        h[r] = nn + zz * (h[r] - nn);
      }

      // hi = rne(h) (also the y value), lo = trunc(h - hi)
      us4 hiw, low;
      #pragma unroll
      for (int r = 0; r < 4; ++r) {
        unsigned int u = __float_as_uint(h[r]);
        unsigned short hv = (unsigned short)((u + 0x7fffu + ((u >> 16) & 1u)) >> 16);
        hiw[r] = hv;
        float hf = __uint_as_float(((unsigned int)hv) << 16);
        low[r] = (unsigned short)(__float_as_uint(h[r] - hf) >> 16);
      }
      const int np = 1 - p;
      *(us4*)&hbuf[g][np][0][n15][mu] = hiw;
      *(us4*)&hbuf[g][np][1][n15][mu] = low;
      if (g < 3) {
        *(us4*)&ybuf[g][p][n15][mu] = hiw;
      } else if (t == TT - 1) {
        *(f4*)&hlast[((size_t)stack * BB + b0 + n15) * 64 + mu] = h;
      }
    }
    __syncthreads();
  }
}

// ---------------- FC head ----------------
__global__ __launch_bounds__(128) void head(
    const float* __restrict__ hlast,
    const float* __restrict__ W1, const float* __restrict__ b1,
    const float* __restrict__ g1, const float* __restrict__ be1,
    const float* __restrict__ m1, const float* __restrict__ v1,
    const float* __restrict__ W2, const float* __restrict__ b2,
    const float* __restrict__ g2, const float* __restrict__ be2,
    const float* __restrict__ m2, const float* __restrict__ v2,
    const float* __restrict__ W3, const float* __restrict__ b3,
    float* __restrict__ out) {
  const int b = blockIdx.x;
  const int j = threadIdx.x;
  __shared__ float xin[128];
  __shared__ float y1[128];
  __shared__ float y2[128];
  xin[j] = (j < 64) ? hlast[(size_t)b * 64 + j]
                    : hlast[(size_t)BB * 64 + (size_t)b * 64 + (j - 64)];
  __syncthreads();
  float acc = b1[j];
  #pragma unroll 8
  for (int k = 0; k < 128; ++k) acc = fmaf(W1[j * 128 + k], xin[k], acc);
  float sc = g1[j] * rsqrtf(v1[j] + 1e-5f);
  y1[j] = fmaxf(0.f, (acc - m1[j]) * sc + be1[j]);
  __syncthreads();
  acc = b2[j];
  #pragma unroll 8
  for (int k = 0; k < 128; ++k) acc = fmaf(W2[j * 128 + k], y1[k], acc);
  sc = g2[j] * rsqrtf(v2[j] + 1e-5f);
  y2[j] = fmaxf(0.f, (acc - m2[j]) * sc + be2[j]);
  __syncthreads();
  if (j < 2) {
    float a = b3[j];
    #pragma unroll 8
    for (int k = 0; k < 128; ++k) a = fmaf(W3[j * 128 + k], y2[k], a);
    out[(size_t)b * 2 + j] = a;
  }
}

}  // namespace

extern "C" void kernel_launch(void* const* d_in, const int* in_sizes, int n_in,
                              void* d_out, int out_size, void* d_ws, size_t ws_size,
                              hipStream_t stream) {
  (void)in_sizes; (void)n_in; (void)out_size; (void)ws_size;
  const float* sent   = (const float*)d_in[0];
  const float* price  = (const float*)d_in[1];
  const float* s_Wih0 = (const float*)d_in[2];
  const float* s_Wih  = (const float*)d_in[3];
  const float* s_Whh  = (const float*)d_in[4];
  const float* s_bih  = (const float*)d_in[5];
  const float* s_bhh  = (const float*)d_in[6];
  const float* p_Wih0 = (const float*)d_in[7];
  const float* p_Wih  = (const float*)d_in[8];
  const float* p_Whh  = (const float*)d_in[9];
  const float* p_bih  = (const float*)d_in[10];
  const float* p_bhh  = (const float*)d_in[11];
  const float* fc1_W  = (const float*)d_in[12];
  const float* fc1_b  = (const float*)d_in[13];
  const float* bn1_g  = (const float*)d_in[14];
  const float* bn1_b  = (const float*)d_in[15];
  const float* bn1_m  = (const float*)d_in[16];
  const float* bn1_v  = (const float*)d_in[17];
  const float* fc2_W  = (const float*)d_in[18];
  const float* fc2_b  = (const float*)d_in[19];
  const float* bn2_g  = (const float*)d_in[20];
  const float* bn2_b  = (const float*)d_in[21];
  const float* bn2_m  = (const float*)d_in[22];
  const float* bn2_v  = (const float*)d_in[23];
  const float* fc3_W  = (const float*)d_in[24];
  const float* fc3_b  = (const float*)d_in[25];
  float* out = (float*)d_out;

  float* hlast = (float*)d_ws;  // [2, B, 64] f32

  gru_all<<<dim3(256), dim3(1024), 0, stream>>>(
      sent, price, s_Wih0, p_Wih0,
      s_Wih, p_Wih, s_Whh, p_Whh,
      s_bih, p_bih, s_bhh, p_bhh, hlast);

  head<<<dim3(BB), dim3(128), 0, stream>>>(
      hlast, fc1_W, fc1_b, bn1_g, bn1_b, bn1_m, bn1_v,
      fc2_W, fc2_b, bn2_g, bn2_b, bn2_m, bn2_v, fc3_W, fc3_b, out);
}

// Round 4
// 850.511 us; speedup vs baseline: 1.0317x; 1.0317x over previous
//
#include <hip/hip_runtime.h>

namespace {

constexpr int BB = 2048;   // batch
constexpr int TT = 256;    // time steps

typedef __attribute__((ext_vector_type(8))) short bf8;          // 8 bf16 (4 VGPR)
typedef __attribute__((ext_vector_type(4))) float f4;           // MFMA acc
typedef __attribute__((ext_vector_type(4))) unsigned short us4;

#define MFMA16(a, b, c) __builtin_amdgcn_mfma_f32_16x16x32_bf16((a), (b), (c), 0, 0, 0)

// Cross-wave LDS handoff needs only lgkmcnt; do NOT drain vmcnt (global
// prefetch/stores stay in flight across the barrier — the R2 stall).
#define BAR_LDS() asm volatile("s_waitcnt lgkmcnt(0)\n\ts_barrier" ::: "memory")

__device__ __forceinline__ unsigned short f2bf_rne(float f) {
  unsigned int x = __float_as_uint(f);
  return (unsigned short)((x + 0x7fffu + ((x >> 16) & 1u)) >> 16);
}
__device__ __forceinline__ float sigm(float x) {
  return __builtin_amdgcn_rcpf(1.f + __expf(-x));
}
__device__ __forceinline__ float tanh_f(float x) {
  float e = __expf(2.f * x);
  return 1.f - 2.f * __builtin_amdgcn_rcpf(e + 1.f);
}
__device__ __forceinline__ void mk_hilo(float v, short& hi, short& lo) {
  unsigned int u = __float_as_uint(v);
  hi = (short)(u >> 16);
  float r = v - __uint_as_float(u & 0xffff0000u);
  lo = (short)(__float_as_uint(r) >> 16);
}

// ---------------- layers 1..3: full MFMA recurrence, in-place on buf ----------------
__global__ __launch_bounds__(256, 1) void gru_ln(
    const float* __restrict__ Wxs, const float* __restrict__ Whs,
    const float* __restrict__ bis, const float* __restrict__ bhs,
    const float* __restrict__ Wxp, const float* __restrict__ Whp,
    const float* __restrict__ bip, const float* __restrict__ bhp,
    unsigned short* __restrict__ buf, float* __restrict__ hlast, int write_y) {
  const int tid = threadIdx.x;
  const int w = tid >> 6, lane = tid & 63;
  const int n15 = lane & 15, g = lane >> 4;
  const int blk = blockIdx.x, stack = blk >> 7;
  const int b0 = (blk & 127) * 16;
  const float* Wx = stack ? Wxp : Wxs;
  const float* Wh = stack ? Whp : Whs;
  const float* bi = stack ? bip : bis;
  const float* bh = stack ? bhp : bhs;
  unsigned short* xb = buf + (size_t)blk * TT * 1024;  // [t][n][64] bf16

  __shared__ unsigned short hbuf[2][2][16][72];  // [phase][hi/lo][n][64+8pad]

  // ---- weight fragments in registers (A-frag: row = lane&15, k = g*8+j contiguous)
  bf8 wxh[3][2], wxl[3][2], whh[3][2], whl[3][2];
  const int mrow = 16 * w + n15;  // wave w owns Mtiles {w, 4+w, 8+w}
  #pragma unroll
  for (int i = 0; i < 3; ++i) {
    #pragma unroll
    for (int kt = 0; kt < 2; ++kt) {
      const float* px_ = Wx + (size_t)(i * 64 + mrow) * 64 + kt * 32 + g * 8;
      const float* ph_ = Wh + (size_t)(i * 64 + mrow) * 64 + kt * 32 + g * 8;
      f4 xa = *(const f4*)px_, xc = *(const f4*)(px_ + 4);
      f4 ha = *(const f4*)ph_, hc = *(const f4*)(ph_ + 4);
      bf8 h1, l1, h2, l2;
      #pragma unroll
      for (int j = 0; j < 8; ++j) {
        float vx = (j < 4) ? xa[j] : xc[j - 4];
        float vh = (j < 4) ? ha[j] : hc[j - 4];
        short a_, b_;
        mk_hilo(vx, a_, b_); h1[j] = a_; l1[j] = b_;
        mk_hilo(vh, a_, b_); h2[j] = a_; l2[j] = b_;
      }
      wxh[i][kt] = h1; wxl[i][kt] = l1; whh[i][kt] = h2; whl[i][kt] = l2;
    }
  }

  const int mu = 16 * w + 4 * g;  // C-layout unit base for this lane's 4 regs
  f4 bR, bZ, bNx, bNh;
  #pragma unroll
  for (int r = 0; r < 4; ++r) {
    bR[r]  = bi[mu + r] + bh[mu + r];
    bZ[r]  = bi[64 + mu + r] + bh[64 + mu + r];
    bNx[r] = bi[128 + mu + r];
    bNh[r] = bh[128 + mu + r];
  }
  const f4 z4f = {0.f, 0.f, 0.f, 0.f};

  f4 h = z4f;
  {
    us4 z4 = {0, 0, 0, 0};
    *(us4*)&hbuf[0][0][n15][mu] = z4;
    *(us4*)&hbuf[0][1][n15][mu] = z4;
  }
  // 2-deep x prefetch (B-frag: col = lane&15, k = g*8+j contiguous)
  bf8 xf[2][2];
  xf[0][0] = *(const bf8*)(xb + n15 * 64 + g * 8);
  xf[0][1] = *(const bf8*)(xb + n15 * 64 + 32 + g * 8);
  xf[1][0] = *(const bf8*)(xb + (size_t)1024 + n15 * 64 + g * 8);
  xf[1][1] = *(const bf8*)(xb + (size_t)1024 + n15 * 64 + 32 + g * 8);
  __syncthreads();

  #pragma unroll 2
  for (int t = 0; t < TT; ++t) {
    const int pi = t & 1;
    bf8 xc0 = xf[pi][0], xc1 = xf[pi][1];
    if (t + 2 < TT) {
      xf[pi][0] = *(const bf8*)(xb + (size_t)(t + 2) * 1024 + n15 * 64 + g * 8);
      xf[pi][1] = *(const bf8*)(xb + (size_t)(t + 2) * 1024 + n15 * 64 + 32 + g * 8);
    }
    bf8 hh0 = *(const bf8*)&hbuf[pi][0][n15][g * 8];
    bf8 hh1 = *(const bf8*)&hbuf[pi][0][n15][32 + g * 8];
    bf8 hl0 = *(const bf8*)&hbuf[pi][1][n15][g * 8];
    bf8 hl1 = *(const bf8*)&hbuf[pi][1][n15][32 + g * 8];

    // two partial accumulators per gate -> dependent-MFMA chain depth 4 not 8
    f4 aR = bR, aZ = bZ, aNx = bNx, aNh = bNh;
    f4 aR2 = z4f, aZ2 = z4f, aNh2 = z4f;
    aR  = MFMA16(wxh[0][0], xc0, aR);  aR  = MFMA16(wxh[0][1], xc1, aR);
    aZ  = MFMA16(wxh[1][0], xc0, aZ);  aZ  = MFMA16(wxh[1][1], xc1, aZ);
    aNx = MFMA16(wxh[2][0], xc0, aNx); aNx = MFMA16(wxh[2][1], xc1, aNx);
    aR  = MFMA16(wxl[0][0], xc0, aR);  aR  = MFMA16(wxl[0][1], xc1, aR);
    aZ  = MFMA16(wxl[1][0], xc0, aZ);  aZ  = MFMA16(wxl[1][1], xc1, aZ);
    aNx = MFMA16(wxl[2][0], xc0, aNx); aNx = MFMA16(wxl[2][1], xc1, aNx);

    aR  = MFMA16(whh[0][0], hh0, aR);  aR  = MFMA16(whh[0][1], hh1, aR);
    aZ  = MFMA16(whh[1][0], hh0, aZ);  aZ  = MFMA16(whh[1][1], hh1, aZ);
    aNh = MFMA16(whh[2][0], hh0, aNh); aNh = MFMA16(whh[2][1], hh1, aNh);
    aR2  = MFMA16(whl[0][0], hh0, aR2);  aR2  = MFMA16(whl[0][1], hh1, aR2);
    aZ2  = MFMA16(whl[1][0], hh0, aZ2);  aZ2  = MFMA16(whl[1][1], hh1, aZ2);
    aNh2 = MFMA16(whl[2][0], hh0, aNh2); aNh2 = MFMA16(whl[2][1], hh1, aNh2);
    aR2  = MFMA16(whh[0][0], hl0, aR2);  aR2  = MFMA16(whh[0][1], hl1, aR2);
    aZ2  = MFMA16(whh[1][0], hl0, aZ2);  aZ2  = MFMA16(whh[1][1], hl1, aZ2);
    aNh2 = MFMA16(whh[2][0], hl0, aNh2); aNh2 = MFMA16(whh[2][1], hl1, aNh2);

    #pragma unroll
    for (int r = 0; r < 4; ++r) {
      float rr = sigm(aR[r] + aR2[r]);
      float zz = sigm(aZ[r] + aZ2[r]);
      float nn = tanh_f(aNx[r] + rr * (aNh[r] + aNh2[r]));
      h[r] = nn + zz * (h[r] - nn);
    }

    us4 hiw, low;
    #pragma unroll
    for (int r = 0; r < 4; ++r) {
      unsigned int u = __float_as_uint(h[r]);
      hiw[r] = (unsigned short)(u >> 16);
      float res = h[r] - __uint_as_float(u & 0xffff0000u);
      low[r] = (unsigned short)(__float_as_uint(res) >> 16);
    }
    const int q = pi ^ 1;
    *(us4*)&hbuf[q][0][n15][mu] = hiw;
    *(us4*)&hbuf[q][1][n15][mu] = low;

    if (write_y) {
      us4 yw;
      #pragma unroll
      for (int r = 0; r < 4; ++r) yw[r] = f2bf_rne(h[r]);
      *(us4*)(xb + (size_t)t * 1024 + n15 * 64 + mu) = yw;
    } else if (t == TT - 1) {
      *(f4*)(hlast + ((size_t)stack * BB + b0 + n15) * 64 + mu) = h;
    }
    BAR_LDS();
  }
}

// ---------------- layer 0: x-projection (K=1/4) via VALU, h via MFMA ----------------
__global__ __launch_bounds__(256, 1) void gru_l0(
    const float* __restrict__ xs, const float* __restrict__ xp,
    const float* __restrict__ W0s, const float* __restrict__ W0p,
    const float* __restrict__ Whs, const float* __restrict__ Whp,
    const float* __restrict__ bis, const float* __restrict__ bhs,
    const float* __restrict__ bip, const float* __restrict__ bhp,
    unsigned short* __restrict__ buf) {
  const int tid = threadIdx.x;
  const int w = tid >> 6, lane = tid & 63;
  const int n15 = lane & 15, g = lane >> 4;
  const int blk = blockIdx.x, stack = blk >> 7;
  const int b0 = (blk & 127) * 16;
  const float* W0 = stack ? W0p : W0s;
  const float* Wh = stack ? Whp : Whs;
  const float* bi = stack ? bip : bis;
  const float* bh = stack ? bhp : bhs;
  unsigned short* xb = buf + (size_t)blk * TT * 1024;

  __shared__ unsigned short hbuf[2][2][16][72];

  bf8 whh[3][2], whl[3][2];
  const int mrow = 16 * w + n15;
  #pragma unroll
  for (int i = 0; i < 3; ++i) {
    #pragma unroll
    for (int kt = 0; kt < 2; ++kt) {
      const float* ph_ = Wh + (size_t)(i * 64 + mrow) * 64 + kt * 32 + g * 8;
      f4 ha = *(const f4*)ph_, hc = *(const f4*)(ph_ + 4);
      bf8 h2, l2;
      #pragma unroll
      for (int j = 0; j < 8; ++j) {
        float vh = (j < 4) ? ha[j] : hc[j - 4];
        short a_, b_;
        mk_hilo(vh, a_, b_); h2[j] = a_; l2[j] = b_;
      }
      whh[i][kt] = h2; whl[i][kt] = l2;
    }
  }

  const int mu = 16 * w + 4 * g;
  f4 bR, bZ, bNx, bNh;
  float w0[3][4][4];
  #pragma unroll
  for (int i = 0; i < 3; ++i) {
    #pragma unroll
    for (int r = 0; r < 4; ++r) {
      const int m = i * 64 + mu + r;
      if (stack) {
        f4 t4 = *(const f4*)(W0 + (size_t)m * 4);
        w0[i][r][0] = t4[0]; w0[i][r][1] = t4[1]; w0[i][r][2] = t4[2]; w0[i][r][3] = t4[3];
      } else {
        w0[i][r][0] = W0[m]; w0[i][r][1] = 0.f; w0[i][r][2] = 0.f; w0[i][r][3] = 0.f;
      }
    }
  }
  #pragma unroll
  for (int r = 0; r < 4; ++r) {
    bR[r]  = bi[mu + r] + bh[mu + r];
    bZ[r]  = bi[64 + mu + r] + bh[64 + mu + r];
    bNx[r] = bi[128 + mu + r];
    bNh[r] = bh[128 + mu + r];
  }
  const f4 z4f = {0.f, 0.f, 0.f, 0.f};

  f4 h = z4f;
  {
    us4 z4 = {0, 0, 0, 0};
    *(us4*)&hbuf[0][0][n15][mu] = z4;
    *(us4*)&hbuf[0][1][n15][mu] = z4;
  }
  const size_t row = (size_t)(b0 + n15);
  float px[4];
  if (stack) {
    f4 t4 = *(const f4*)(xp + row * TT * 4);
    px[0] = t4[0]; px[1] = t4[1]; px[2] = t4[2]; px[3] = t4[3];
  } else {
    px[0] = xs[row * TT]; px[1] = px[2] = px[3] = 0.f;
  }
  __syncthreads();

  #pragma unroll 1
  for (int t = 0; t < TT; ++t) {
    float xc0 = px[0], xc1 = px[1], xc2 = px[2], xc3 = px[3];
    if (t + 1 < TT) {
      if (stack) {
        f4 t4 = *(const f4*)(xp + (row * TT + t + 1) * 4);
        px[0] = t4[0]; px[1] = t4[1]; px[2] = t4[2]; px[3] = t4[3];
      } else {
        px[0] = xs[row * TT + t + 1];
      }
    }
    const int pi = t & 1;
    bf8 hh0 = *(const bf8*)&hbuf[pi][0][n15][g * 8];
    bf8 hh1 = *(const bf8*)&hbuf[pi][0][n15][32 + g * 8];
    bf8 hl0 = *(const bf8*)&hbuf[pi][1][n15][g * 8];
    bf8 hl1 = *(const bf8*)&hbuf[pi][1][n15][32 + g * 8];

    f4 aR = bR, aZ = bZ, aNx = bNx, aNh = bNh;
    f4 aR2 = z4f, aZ2 = z4f, aNh2 = z4f;
    #pragma unroll
    for (int r = 0; r < 4; ++r) {
      aR[r]  += w0[0][r][0] * xc0 + w0[0][r][1] * xc1 + w0[0][r][2] * xc2 + w0[0][r][3] * xc3;
      aZ[r]  += w0[1][r][0] * xc0 + w0[1][r][1] * xc1 + w0[1][r][2] * xc2 + w0[1][r][3] * xc3;
      aNx[r] += w0[2][r][0] * xc0 + w0[2][r][1] * xc1 + w0[2][r][2] * xc2 + w0[2][r][3] * xc3;
    }
    aR  = MFMA16(whh[0][0], hh0, aR);  aR  = MFMA16(whh[0][1], hh1, aR);
    aZ  = MFMA16(whh[1][0], hh0, aZ);  aZ  = MFMA16(whh[1][1], hh1, aZ);
    aNh = MFMA16(whh[2][0], hh0, aNh); aNh = MFMA16(whh[2][1], hh1, aNh);
    aR2  = MFMA16(whl[0][0], hh0, aR2);  aR2  = MFMA16(whl[0][1], hh1, aR2);
    aZ2  = MFMA16(whl[1][0], hh0, aZ2);  aZ2  = MFMA16(whl[1][1], hh1, aZ2);
    aNh2 = MFMA16(whl[2][0], hh0, aNh2); aNh2 = MFMA16(whl[2][1], hh1, aNh2);
    aR2  = MFMA16(whh[0][0], hl0, aR2);  aR2  = MFMA16(whh[0][1], hl1, aR2);
    aZ2  = MFMA16(whh[1][0], hl0, aZ2);  aZ2  = MFMA16(whh[1][1], hl1, aZ2);
    aNh2 = MFMA16(whh[2][0], hl0, aNh2); aNh2 = MFMA16(whh[2][1], hl1, aNh2);

    #pragma unroll
    for (int r = 0; r < 4; ++r) {
      float rr = sigm(aR[r] + aR2[r]);
      float zz = sigm(aZ[r] + aZ2[r]);
      float nn = tanh_f(aNx[r] + rr * (aNh[r] + aNh2[r]));
      h[r] = nn + zz * (h[r] - nn);
    }

    us4 hiw, low;
    #pragma unroll
    for (int r = 0; r < 4; ++r) {
      unsigned int u = __float_as_uint(h[r]);
      hiw[r] = (unsigned short)(u >> 16);
      float res = h[r] - __uint_as_float(u & 0xffff0000u);
      low[r] = (unsigned short)(__float_as_uint(res) >> 16);
    }
    const int q = pi ^ 1;
    *(us4*)&hbuf[q][0][n15][mu] = hiw;
    *(us4*)&hbuf[q][1][n15][mu] = low;

    us4 yw;
    #pragma unroll
    for (int r = 0; r < 4; ++r) yw[r] = f2bf_rne(h[r]);
    *(us4*)(xb + (size_t)t * 1024 + n15 * 64 + mu) = yw;
    BAR_LDS();
  }
}

// ---------------- FC head ----------------
__global__ __launch_bounds__(128) void head(
    const float* __restrict__ hlast,
    const float* __restrict__ W1, const float* __restrict__ b1,
    const float* __restrict__ g1, const float* __restrict__ be1,
    const float* __restrict__ m1, const float* __restrict__ v1,
    const float* __restrict__ W2, const float* __restrict__ b2,
    const float* __restrict__ g2, const float* __restrict__ be2,
    const float* __restrict__ m2, const float* __restrict__ v2,
    const float* __restrict__ W3, const float* __restrict__ b3,
    float* __restrict__ out) {
  const int b = blockIdx.x;
  const int j = threadIdx.x;
  __shared__ float xin[128];
  __shared__ float y1[128];
  __shared__ float y2[128];
  xin[j] = (j < 64) ? hlast[(size_t)b * 64 + j]
                    : hlast[(size_t)BB * 64 + (size_t)b * 64 + (j - 64)];
  __syncthreads();
  float acc = b1[j];
  #pragma unroll 8
  for (int k = 0; k < 128; ++k) acc = fmaf(W1[j * 128 + k], xin[k], acc);
  float sc = g1[j] * rsqrtf(v1[j] + 1e-5f);
  y1[j] = fmaxf(0.f, (acc - m1[j]) * sc + be1[j]);
  __syncthreads();
  acc = b2[j];
  #pragma unroll 8
  for (int k = 0; k < 128; ++k) acc = fmaf(W2[j * 128 + k], y1[k], acc);
  sc = g2[j] * rsqrtf(v2[j] + 1e-5f);
  y2[j] = fmaxf(0.f, (acc - m2[j]) * sc + be2[j]);
  __syncthreads();
  if (j < 2) {
    float a = b3[j];
    #pragma unroll 8
    for (int k = 0; k < 128; ++k) a = fmaf(W3[j * 128 + k], y2[k], a);
    out[(size_t)b * 2 + j] = a;
  }
}

}  // namespace

extern "C" void kernel_launch(void* const* d_in, const int* in_sizes, int n_in,
                              void* d_out, int out_size, void* d_ws, size_t ws_size,
                              hipStream_t stream) {
  (void)in_sizes; (void)n_in; (void)out_size; (void)ws_size;
  const float* sent   = (const float*)d_in[0];
  const float* price  = (const float*)d_in[1];
  const float* s_Wih0 = (const float*)d_in[2];
  const float* s_Wih  = (const float*)d_in[3];
  const float* s_Whh  = (const float*)d_in[4];
  const float* s_bih  = (const float*)d_in[5];
  const float* s_bhh  = (const float*)d_in[6];
  const float* p_Wih0 = (const float*)d_in[7];
  const float* p_Wih  = (const float*)d_in[8];
  const float* p_Whh  = (const float*)d_in[9];
  const float* p_bih  = (const float*)d_in[10];
  const float* p_bhh  = (const float*)d_in[11];
  const float* fc1_W  = (const float*)d_in[12];
  const float* fc1_b  = (const float*)d_in[13];
  const float* bn1_g  = (const float*)d_in[14];
  const float* bn1_b  = (const float*)d_in[15];
  const float* bn1_m  = (const float*)d_in[16];
  const float* bn1_v  = (const float*)d_in[17];
  const float* fc2_W  = (const float*)d_in[18];
  const float* fc2_b  = (const float*)d_in[19];
  const float* bn2_g  = (const float*)d_in[20];
  const float* bn2_b  = (const float*)d_in[21];
  const float* bn2_m  = (const float*)d_in[22];
  const float* bn2_v  = (const float*)d_in[23];
  const float* fc3_W  = (const float*)d_in[24];
  const float* fc3_b  = (const float*)d_in[25];
  float* out = (float*)d_out;

  unsigned short* buf = (unsigned short*)d_ws;                  // [256 blk][256 t][16 n][64 u] bf16
  float* hlast = (float*)(buf + (size_t)256 * TT * 1024);       // [2,B,64] f32

  gru_l0<<<dim3(256), dim3(256), 0, stream>>>(
      sent, price, s_Wih0, p_Wih0, s_Whh, p_Whh,
      s_bih, s_bhh, p_bih, p_bhh, buf);

  for (int l = 1; l <= 3; ++l) {
    gru_ln<<<dim3(256), dim3(256), 0, stream>>>(
        s_Wih + (size_t)(l - 1) * 192 * 64, s_Whh + (size_t)l * 192 * 64,
        s_bih + l * 192, s_bhh + l * 192,
        p_Wih + (size_t)(l - 1) * 192 * 64, p_Whh + (size_t)l * 192 * 64,
        p_bih + l * 192, p_bhh + l * 192,
        buf, hlast, (l < 3) ? 1 : 0);
  }

  head<<<dim3(BB), dim3(128), 0, stream>>>(
      hlast, fc1_W, fc1_b, bn1_g, bn1_b, bn1_m, bn1_v,
      fc2_W, fc2_b, bn2_g, bn2_b, bn2_m, bn2_v, fc3_W, fc3_b, out);
}

// Round 5
// 698.596 us; speedup vs baseline: 1.2561x; 1.2175x over previous
//
#include <hip/hip_runtime.h>

namespace {

constexpr int BB = 2048;   // batch
constexpr int TT = 256;    // time steps

typedef __attribute__((ext_vector_type(8))) short bf8;          // 8 bf16 (4 VGPR)
typedef __attribute__((ext_vector_type(4))) float f4;           // MFMA acc
typedef __attribute__((ext_vector_type(4))) unsigned short us4;

#define MFMA16(a, b, c) __builtin_amdgcn_mfma_f32_16x16x32_bf16((a), (b), (c), 0, 0, 0)

__device__ __forceinline__ float sigm(float x) {
  return __builtin_amdgcn_rcpf(1.f + __expf(-x));
}
__device__ __forceinline__ float tanh_f(float x) {
  float e = __expf(2.f * x);
  return 1.f - 2.f * __builtin_amdgcn_rcpf(e + 1.f);
}
__device__ __forceinline__ void mk_hilo(float v, short& hi, short& lo) {
  unsigned int u = __float_as_uint(v);
  hi = (short)(u >> 16);
  float r = v - __uint_as_float(u & 0xffff0000u);
  lo = (short)(__float_as_uint(r) >> 16);
}

// ACQUIRE poll of an LDS counter (wave-uniform). s_sleep keeps the LDS pipe free.
__device__ __forceinline__ void waitq(const unsigned* c, unsigned tgt) {
  while (__hip_atomic_load(c, __ATOMIC_ACQUIRE, __HIP_MEMORY_SCOPE_WORKGROUP) < tgt)
    __builtin_amdgcn_s_sleep(1);
}

// ============ two GRU layers, free-running pipelined in one block ============
// Block = 512 threads = 8 waves = 2 quads. Quad gq runs layer L = 2*MODE+gq.
// No __syncthreads in the time loop: quads sync via LDS sum-counters
// (RELEASE ds_add by lane 0 after writes; ACQUIRE polls by consumers).
// Quad skew is bounded: h double-buffer (parity), y ring depth 4 with
// backpressure (producer waits consumer >= t-3).
template <int MODE>
__global__ __launch_bounds__(512, 2) void gru_pair(
    const float* __restrict__ xs, const float* __restrict__ xp,
    const float* __restrict__ W0s, const float* __restrict__ W0p,
    const float* __restrict__ Wihs, const float* __restrict__ Wihp,  // [3][192][64]
    const float* __restrict__ Whhs, const float* __restrict__ Whhp,  // [4][192][64]
    const float* __restrict__ bihs, const float* __restrict__ bihp,  // [4][192]
    const float* __restrict__ bhhs, const float* __restrict__ bhhp,
    unsigned short* __restrict__ y1buf,   // [256 blk][256 t][16 n][64 u] bf16
    float* __restrict__ hlast) {
  const int tid = threadIdx.x;
  const int Wv = tid >> 6, lane = tid & 63;
  const int gq = Wv >> 2, w = Wv & 3;
  const int n15 = lane & 15, q = lane >> 4;
  const int blk = blockIdx.x, stack = blk >> 7;
  const int b0 = (blk & 127) * 16;
  const int L = 2 * MODE + gq;

  const float* Wih = stack ? Wihp : Wihs;
  const float* Whh = stack ? Whhp : Whhs;
  const float* bi = (stack ? bihp : bihs) + L * 192;
  const float* bh = (stack ? bhhp : bhhs) + L * 192;
  const float* Wh = Whh + (size_t)L * 192 * 64;
  const float* Wx = (L >= 1) ? (Wih + (size_t)(L - 1) * 192 * 64) : nullptr;
  unsigned short* xb = y1buf + (size_t)blk * TT * 1024;

  __shared__ unsigned short hb[2][2][2][16][72];  // [gq][parity][hi/lo][n][64+8]
  __shared__ unsigned short yb[4][16][72];        // y ring, quad0 -> quad1
  __shared__ unsigned qdone[2];

  for (int e = tid; e < 2 * 2 * 2 * 16 * 72; e += 512) ((unsigned short*)hb)[e] = 0;
  if (tid < 2) qdone[tid] = 0;
  __syncthreads();  // only barrier in the kernel

  const int mrow = 16 * w + n15;   // A-frag row; wave w owns Mtiles {w, w+4, w+8}
  const int mu = 16 * w + 4 * q;   // C-layout unit base for this lane's 4 regs

  f4 bR, bZ, bNx, bNh;
  #pragma unroll
  for (int r = 0; r < 4; ++r) {
    bR[r]  = bi[mu + r] + bh[mu + r];
    bZ[r]  = bi[64 + mu + r] + bh[64 + mu + r];
    bNx[r] = bi[128 + mu + r];
    bNh[r] = bh[128 + mu + r];
  }
  f4 h = {0.f, 0.f, 0.f, 0.f};

  if (gq == 0) {
    // ---------------- quad 0: layer 2*MODE ----------------
    bf8 whh_[3][2], whl_[3][2], wxh_[3][2], wxl_[3][2];
    float w0[3][4][4];
    #pragma unroll
    for (int i = 0; i < 3; ++i) {
      #pragma unroll
      for (int kt = 0; kt < 2; ++kt) {
        const float* ph_ = Wh + (size_t)(i * 64 + mrow) * 64 + kt * 32 + q * 8;
        f4 ha = *(const f4*)ph_, hc = *(const f4*)(ph_ + 4);
        bf8 h2, l2;
        #pragma unroll
        for (int j = 0; j < 8; ++j) {
          float vh = (j < 4) ? ha[j] : hc[j - 4];
          short a_, b_; mk_hilo(vh, a_, b_); h2[j] = a_; l2[j] = b_;
        }
        whh_[i][kt] = h2; whl_[i][kt] = l2;
        if (MODE == 1) {
          const float* px_ = Wx + (size_t)(i * 64 + mrow) * 64 + kt * 32 + q * 8;
          f4 xa = *(const f4*)px_, xc = *(const f4*)(px_ + 4);
          bf8 h1, l1;
          #pragma unroll
          for (int j = 0; j < 8; ++j) {
            float vx = (j < 4) ? xa[j] : xc[j - 4];
            short a_, b_; mk_hilo(vx, a_, b_); h1[j] = a_; l1[j] = b_;
          }
          wxh_[i][kt] = h1; wxl_[i][kt] = l1;
        }
      }
    }
    if (MODE == 0) {
      const float* W0 = stack ? W0p : W0s;
      #pragma unroll
      for (int i = 0; i < 3; ++i)
        #pragma unroll
        for (int r = 0; r < 4; ++r) {
          const int m = i * 64 + mu + r;
          if (stack) {
            f4 t4 = *(const f4*)(W0 + (size_t)m * 4);
            w0[i][r][0] = t4[0]; w0[i][r][1] = t4[1]; w0[i][r][2] = t4[2]; w0[i][r][3] = t4[3];
          } else {
            w0[i][r][0] = W0[m]; w0[i][r][1] = 0.f; w0[i][r][2] = 0.f; w0[i][r][3] = 0.f;
          }
        }
    }

    const int in_dim = stack ? 4 : 1;
    const size_t xrow = (size_t)(b0 + n15);
    float px[4] = {0.f, 0.f, 0.f, 0.f};
    bf8 xf0 = {}, xf1 = {};
    if (MODE == 0) {
      if (stack) { f4 t4 = *(const f4*)(xp + xrow * TT * 4); px[0]=t4[0]; px[1]=t4[1]; px[2]=t4[2]; px[3]=t4[3]; }
      else       { px[0] = xs[xrow * TT]; }
    } else {
      xf0 = *(const bf8*)(xb + n15 * 64 + q * 8);
      xf1 = *(const bf8*)(xb + n15 * 64 + 32 + q * 8);
    }

    #pragma unroll 1
    for (int t = 0; t < TT; ++t) {
      waitq(&qdone[0], 4u * (unsigned)t);  // quad peers done step t-1
      bf8 hh0 = *(const bf8*)&hb[0][t & 1][0][n15][q * 8];
      bf8 hh1 = *(const bf8*)&hb[0][t & 1][0][n15][32 + q * 8];
      bf8 hl0 = *(const bf8*)&hb[0][t & 1][1][n15][q * 8];
      bf8 hl1 = *(const bf8*)&hb[0][t & 1][1][n15][32 + q * 8];

      f4 aR = bR, aZ = bZ, aNx = bNx, aNh = bNh;
      if (MODE == 0) {
        float xc0 = px[0], xc1 = px[1], xc2 = px[2], xc3 = px[3];
        if (t + 1 < TT) {
          if (stack) { f4 t4 = *(const f4*)(xp + (xrow * TT + t + 1) * 4); px[0]=t4[0]; px[1]=t4[1]; px[2]=t4[2]; px[3]=t4[3]; }
          else       { px[0] = xs[xrow * TT + t + 1]; }
        }
        #pragma unroll 1
        for (int d = 0; d < in_dim; ++d) {
          float xv = (d == 0) ? xc0 : (d == 1) ? xc1 : (d == 2) ? xc2 : xc3;
          #pragma unroll
          for (int r = 0; r < 4; ++r) {
            aR[r]  = fmaf(w0[0][r][d], xv, aR[r]);
            aZ[r]  = fmaf(w0[1][r][d], xv, aZ[r]);
            aNx[r] = fmaf(w0[2][r][d], xv, aNx[r]);
          }
        }
      } else {
        bf8 xc0 = xf0, xc1 = xf1;
        if (t + 1 < TT) {
          xf0 = *(const bf8*)(xb + (size_t)(t + 1) * 1024 + n15 * 64 + q * 8);
          xf1 = *(const bf8*)(xb + (size_t)(t + 1) * 1024 + n15 * 64 + 32 + q * 8);
        }
        aR  = MFMA16(wxh_[0][0], xc0, aR);  aR  = MFMA16(wxh_[0][1], xc1, aR);
        aZ  = MFMA16(wxh_[1][0], xc0, aZ);  aZ  = MFMA16(wxh_[1][1], xc1, aZ);
        aNx = MFMA16(wxh_[2][0], xc0, aNx); aNx = MFMA16(wxh_[2][1], xc1, aNx);
        aR  = MFMA16(wxl_[0][0], xc0, aR);  aR  = MFMA16(wxl_[0][1], xc1, aR);
        aZ  = MFMA16(wxl_[1][0], xc0, aZ);  aZ  = MFMA16(wxl_[1][1], xc1, aZ);
        aNx = MFMA16(wxl_[2][0], xc0, aNx); aNx = MFMA16(wxl_[2][1], xc1, aNx);
      }
      aR  = MFMA16(whh_[0][0], hh0, aR);  aR  = MFMA16(whh_[0][1], hh1, aR);
      aZ  = MFMA16(whh_[1][0], hh0, aZ);  aZ  = MFMA16(whh_[1][1], hh1, aZ);
      aNh = MFMA16(whh_[2][0], hh0, aNh); aNh = MFMA16(whh_[2][1], hh1, aNh);
      aR  = MFMA16(whl_[0][0], hh0, aR);  aR  = MFMA16(whl_[0][1], hh1, aR);
      aZ  = MFMA16(whl_[1][0], hh0, aZ);  aZ  = MFMA16(whl_[1][1], hh1, aZ);
      aNh = MFMA16(whl_[2][0], hh0, aNh); aNh = MFMA16(whl_[2][1], hh1, aNh);
      aR  = MFMA16(whh_[0][0], hl0, aR);  aR  = MFMA16(whh_[0][1], hl1, aR);
      aZ  = MFMA16(whh_[1][0], hl0, aZ);  aZ  = MFMA16(whh_[1][1], hl1, aZ);
      aNh = MFMA16(whh_[2][0], hl0, aNh); aNh = MFMA16(whh_[2][1], hl1, aNh);

      #pragma unroll
      for (int r = 0; r < 4; ++r) {
        float rr = sigm(aR[r]);
        float zz = sigm(aZ[r]);
        float nn = tanh_f(aNx[r] + rr * aNh[r]);
        h[r] = nn + zz * (h[r] - nn);
      }
      us4 hiw, low;
      #pragma unroll
      for (int r = 0; r < 4; ++r) {
        unsigned u = __float_as_uint(h[r]);
        unsigned short hv = (unsigned short)((u + 0x7fffu + ((u >> 16) & 1u)) >> 16);
        hiw[r] = hv;
        float hf = __uint_as_float((unsigned)hv << 16);
        low[r] = (unsigned short)(__float_as_uint(h[r] - hf) >> 16);
      }
      *(us4*)&hb[0][(t + 1) & 1][0][n15][mu] = hiw;
      *(us4*)&hb[0][(t + 1) & 1][1][n15][mu] = low;
      if (t >= 4) waitq(&qdone[1], 4u * (unsigned)(t - 3));  // y-ring backpressure
      *(us4*)&yb[t & 3][n15][mu] = hiw;
      if (lane == 0)
        __hip_atomic_fetch_add(&qdone[0], 1u, __ATOMIC_RELEASE, __HIP_MEMORY_SCOPE_WORKGROUP);
    }
  } else {
    // ---------------- quad 1: layer 2*MODE+1 ----------------
    bf8 whh_[3][2], whl_[3][2], wxh_[3][2], wxl_[3][2];
    #pragma unroll
    for (int i = 0; i < 3; ++i) {
      #pragma unroll
      for (int kt = 0; kt < 2; ++kt) {
        const float* ph_ = Wh + (size_t)(i * 64 + mrow) * 64 + kt * 32 + q * 8;
        const float* px_ = Wx + (size_t)(i * 64 + mrow) * 64 + kt * 32 + q * 8;
        f4 ha = *(const f4*)ph_, hc = *(const f4*)(ph_ + 4);
        f4 xa = *(const f4*)px_, xc = *(const f4*)(px_ + 4);
        bf8 h1, l1, h2, l2;
        #pragma unroll
        for (int j = 0; j < 8; ++j) {
          float vh = (j < 4) ? ha[j] : hc[j - 4];
          float vx = (j < 4) ? xa[j] : xc[j - 4];
          short a_, b_;
          mk_hilo(vh, a_, b_); h2[j] = a_; l2[j] = b_;
          mk_hilo(vx, a_, b_); h1[j] = a_; l1[j] = b_;
        }
        whh_[i][kt] = h2; whl_[i][kt] = l2; wxh_[i][kt] = h1; wxl_[i][kt] = l1;
      }
    }

    #pragma unroll 1
    for (int t = 0; t < TT; ++t) {
      waitq(&qdone[1], 4u * (unsigned)t);  // quad peers done step t-1
      bf8 hh0 = *(const bf8*)&hb[1][t & 1][0][n15][q * 8];
      bf8 hh1 = *(const bf8*)&hb[1][t & 1][0][n15][32 + q * 8];
      bf8 hl0 = *(const bf8*)&hb[1][t & 1][1][n15][q * 8];
      bf8 hl1 = *(const bf8*)&hb[1][t & 1][1][n15][32 + q * 8];

      // h-part first: overlaps with producer still finishing y(t)
      f4 aR = bR, aZ = bZ, aNx = bNx, aNh = bNh;
      aR  = MFMA16(whh_[0][0], hh0, aR);  aR  = MFMA16(whh_[0][1], hh1, aR);
      aZ  = MFMA16(whh_[1][0], hh0, aZ);  aZ  = MFMA16(whh_[1][1], hh1, aZ);
      aNh = MFMA16(whh_[2][0], hh0, aNh); aNh = MFMA16(whh_[2][1], hh1, aNh);
      aR  = MFMA16(whl_[0][0], hh0, aR);  aR  = MFMA16(whl_[0][1], hh1, aR);
      aZ  = MFMA16(whl_[1][0], hh0, aZ);  aZ  = MFMA16(whl_[1][1], hh1, aZ);
      aNh = MFMA16(whl_[2][0], hh0, aNh); aNh = MFMA16(whl_[2][1], hh1, aNh);
      aR  = MFMA16(whh_[0][0], hl0, aR);  aR  = MFMA16(whh_[0][1], hl1, aR);
      aZ  = MFMA16(whh_[1][0], hl0, aZ);  aZ  = MFMA16(whh_[1][1], hl1, aZ);
      aNh = MFMA16(whh_[2][0], hl0, aNh); aNh = MFMA16(whh_[2][1], hl1, aNh);

      waitq(&qdone[0], 4u * (unsigned)(t + 1));  // y(t) ready
      bf8 xc0 = *(const bf8*)&yb[t & 3][n15][q * 8];
      bf8 xc1 = *(const bf8*)&yb[t & 3][n15][32 + q * 8];
      aR  = MFMA16(wxh_[0][0], xc0, aR);  aR  = MFMA16(wxh_[0][1], xc1, aR);
      aZ  = MFMA16(wxh_[1][0], xc0, aZ);  aZ  = MFMA16(wxh_[1][1], xc1, aZ);
      aNx = MFMA16(wxh_[2][0], xc0, aNx); aNx = MFMA16(wxh_[2][1], xc1, aNx);
      aR  = MFMA16(wxl_[0][0], xc0, aR);  aR  = MFMA16(wxl_[0][1], xc1, aR);
      aZ  = MFMA16(wxl_[1][0], xc0, aZ);  aZ  = MFMA16(wxl_[1][1], xc1, aZ);
      aNx = MFMA16(wxl_[2][0], xc0, aNx); aNx = MFMA16(wxl_[2][1], xc1, aNx);

      #pragma unroll
      for (int r = 0; r < 4; ++r) {
        float rr = sigm(aR[r]);
        float zz = sigm(aZ[r]);
        float nn = tanh_f(aNx[r] + rr * aNh[r]);
        h[r] = nn + zz * (h[r] - nn);
      }
      us4 hiw, low;
      #pragma unroll
      for (int r = 0; r < 4; ++r) {
        unsigned u = __float_as_uint(h[r]);
        unsigned short hv = (unsigned short)((u + 0x7fffu + ((u >> 16) & 1u)) >> 16);
        hiw[r] = hv;
        float hf = __uint_as_float((unsigned)hv << 16);
        low[r] = (unsigned short)(__float_as_uint(h[r] - hf) >> 16);
      }
      *(us4*)&hb[1][(t + 1) & 1][0][n15][mu] = hiw;
      *(us4*)&hb[1][(t + 1) & 1][1][n15][mu] = low;
      if (MODE == 0) {
        *(us4*)(xb + (size_t)t * 1024 + n15 * 64 + mu) = hiw;  // y1 -> HBM
      } else if (t == TT - 1) {
        *(f4*)(hlast + ((size_t)stack * BB + b0 + n15) * 64 + mu) = h;
      }
      if (lane == 0)
        __hip_atomic_fetch_add(&qdone[1], 1u, __ATOMIC_RELEASE, __HIP_MEMORY_SCOPE_WORKGROUP);
    }
  }
}

// ---------------- FC head ----------------
__global__ __launch_bounds__(128) void head(
    const float* __restrict__ hlast,
    const float* __restrict__ W1, const float* __restrict__ b1,
    const float* __restrict__ g1, const float* __restrict__ be1,
    const float* __restrict__ m1, const float* __restrict__ v1,
    const float* __restrict__ W2, const float* __restrict__ b2,
    const float* __restrict__ g2, const float* __restrict__ be2,
    const float* __restrict__ m2, const float* __restrict__ v2,
    const float* __restrict__ W3, const float* __restrict__ b3,
    float* __restrict__ out) {
  const int b = blockIdx.x;
  const int j = threadIdx.x;
  __shared__ float xin[128];
  __shared__ float y1[128];
  __shared__ float y2[128];
  xin[j] = (j < 64) ? hlast[(size_t)b * 64 + j]
                    : hlast[(size_t)BB * 64 + (size_t)b * 64 + (j - 64)];
  __syncthreads();
  float acc = b1[j];
  #pragma unroll 8
  for (int k = 0; k < 128; ++k) acc = fmaf(W1[j * 128 + k], xin[k], acc);
  float sc = g1[j] * rsqrtf(v1[j] + 1e-5f);
  y1[j] = fmaxf(0.f, (acc - m1[j]) * sc + be1[j]);
  __syncthreads();
  acc = b2[j];
  #pragma unroll 8
  for (int k = 0; k < 128; ++k) acc = fmaf(W2[j * 128 + k], y1[k], acc);
  sc = g2[j] * rsqrtf(v2[j] + 1e-5f);
  y2[j] = fmaxf(0.f, (acc - m2[j]) * sc + be2[j]);
  __syncthreads();
  if (j < 2) {
    float a = b3[j];
    #pragma unroll 8
    for (int k = 0; k < 128; ++k) a = fmaf(W3[j * 128 + k], y2[k], a);
    out[(size_t)b * 2 + j] = a;
  }
}

}  // namespace

extern "C" void kernel_launch(void* const* d_in, const int* in_sizes, int n_in,
                              void* d_out, int out_size, void* d_ws, size_t ws_size,
                              hipStream_t stream) {
  (void)in_sizes; (void)n_in; (void)out_size; (void)ws_size;
  const float* sent   = (const float*)d_in[0];
  const float* price  = (const float*)d_in[1];
  const float* s_Wih0 = (const float*)d_in[2];
  const float* s_Wih  = (const float*)d_in[3];
  const float* s_Whh  = (const float*)d_in[4];
  const float* s_bih  = (const float*)d_in[5];
  const float* s_bhh  = (const float*)d_in[6];
  const float* p_Wih0 = (const float*)d_in[7];
  const float* p_Wih  = (const float*)d_in[8];
  const float* p_Whh  = (const float*)d_in[9];
  const float* p_bih  = (const float*)d_in[10];
  const float* p_bhh  = (const float*)d_in[11];
  const float* fc1_W  = (const float*)d_in[12];
  const float* fc1_b  = (const float*)d_in[13];
  const float* bn1_g  = (const float*)d_in[14];
  const float* bn1_b  = (const float*)d_in[15];
  const float* bn1_m  = (const float*)d_in[16];
  const float* bn1_v  = (const float*)d_in[17];
  const float* fc2_W  = (const float*)d_in[18];
  const float* fc2_b  = (const float*)d_in[19];
  const float* bn2_g  = (const float*)d_in[20];
  const float* bn2_b  = (const float*)d_in[21];
  const float* bn2_m  = (const float*)d_in[22];
  const float* bn2_v  = (const float*)d_in[23];
  const float* fc3_W  = (const float*)d_in[24];
  const float* fc3_b  = (const float*)d_in[25];
  float* out = (float*)d_out;

  unsigned short* y1buf = (unsigned short*)d_ws;                // [256][256][16][64] bf16
  float* hlast = (float*)(y1buf + (size_t)256 * TT * 1024);     // [2,B,64] f32

  gru_pair<0><<<dim3(256), dim3(512), 0, stream>>>(
      sent, price, s_Wih0, p_Wih0, s_Wih, p_Wih, s_Whh, p_Whh,
      s_bih, p_bih, s_bhh, p_bhh, y1buf, hlast);
  gru_pair<1><<<dim3(256), dim3(512), 0, stream>>>(
      sent, price, s_Wih0, p_Wih0, s_Wih, p_Wih, s_Whh, p_Whh,
      s_bih, p_bih, s_bhh, p_bhh, y1buf, hlast);

  head<<<dim3(BB), dim3(128), 0, stream>>>(
      hlast, fc1_W, fc1_b, bn1_g, bn1_b, bn1_m, bn1_v,
      fc2_W, fc2_b, bn2_g, bn2_b, bn2_m, bn2_v, fc3_W, fc3_b, out);
}

// Round 6
// 425.294 us; speedup vs baseline: 2.0633x; 1.6426x over previous
//
#include <hip/hip_runtime.h>

namespace {

constexpr int BB = 2048;   // batch
constexpr int TT = 256;    // time steps

typedef __attribute__((ext_vector_type(8))) short bf8;          // 8 bf16 (4 VGPR)
typedef __attribute__((ext_vector_type(4))) float f4;           // MFMA acc
typedef __attribute__((ext_vector_type(4))) unsigned short us4;

#define MFMA16(a, b, c) __builtin_amdgcn_mfma_f32_16x16x32_bf16((a), (b), (c), 0, 0, 0)

__device__ __forceinline__ unsigned short f2bf_rne(float f) {
  unsigned int x = __float_as_uint(f);
  return (unsigned short)((x + 0x7fffu + ((x >> 16) & 1u)) >> 16);
}
__device__ __forceinline__ float sigm(float x) {
  return __builtin_amdgcn_rcpf(1.f + __expf(-x));
}
__device__ __forceinline__ float tanh_f(float x) {
  float e = __expf(2.f * x);
  return 1.f - 2.f * __builtin_amdgcn_rcpf(e + 1.f);
}
__device__ __forceinline__ void mk_hilo(float v, short& hi, short& lo) {
  unsigned int u = __float_as_uint(v);
  hi = (short)(u >> 16);
  float r = v - __uint_as_float(u & 0xffff0000u);
  lo = (short)(__float_as_uint(r) >> 16);
}

// ACQUIRE poll of an LDS counter (wave-uniform address).
__device__ __forceinline__ void waitq(const unsigned* c, unsigned tgt) {
  while (__hip_atomic_load(c, __ATOMIC_ACQUIRE, __HIP_MEMORY_SCOPE_WORKGROUP) < tgt)
    __builtin_amdgcn_s_sleep(1);
}

// ============ all 4 GRU layers, free-running pipelined in one block ============
// 1024 threads = 16 waves = 4 quads; quad g = layer g. Sync via LDS sum-counters
// (RELEASE ds_add per wave after writes; ACQUIRE polls). h double-buffered by
// parity; inter-layer y rings depth 4 with backpressure. No __syncthreads in
// the time loop. Numerics: Wh/Wx rne-bf16 hi; h kept as bf16 hi+lo (whh@hl
// compensation) so the recurrence state is ~fp32-accurate.
__global__ __launch_bounds__(1024) void gru_all(
    const float* __restrict__ xs, const float* __restrict__ xp,
    const float* __restrict__ W0s, const float* __restrict__ W0p,
    const float* __restrict__ Wihs, const float* __restrict__ Wihp,  // [3][192][64]
    const float* __restrict__ Whhs, const float* __restrict__ Whhp,  // [4][192][64]
    const float* __restrict__ bihs, const float* __restrict__ bihp,  // [4][192]
    const float* __restrict__ bhhs, const float* __restrict__ bhhp,
    float* __restrict__ hlast) {
  const int tid = threadIdx.x;
  const int Wv = tid >> 6, lane = tid & 63;
  const int g = Wv >> 2, w = Wv & 3;      // quad (=layer), wave-in-quad
  const int n15 = lane & 15, q = lane >> 4;
  const int blk = blockIdx.x, stack = blk >> 7;
  const int b0 = (blk & 127) * 16;

  const float* Wh = (stack ? Whhp : Whhs) + (size_t)g * 192 * 64;
  const float* bi = (stack ? bihp : bihs) + g * 192;
  const float* bh = (stack ? bhhp : bhhs) + g * 192;
  const float* Wx = (stack ? Wihp : Wihs) + (size_t)(g - 1) * 192 * 64;  // g>=1

  __shared__ unsigned short hb[4][2][2][16][72];  // [g][parity][hi/lo][n][64+8]
  __shared__ unsigned short yb[3][4][16][72];     // [g][ring slot][n][64+8]
  __shared__ unsigned qdone[4];

  for (int e = tid; e < 4 * 2 * 2 * 16 * 72; e += 1024) ((unsigned short*)hb)[e] = 0;
  if (tid < 4) qdone[tid] = 0;
  __syncthreads();  // only barrier in the kernel

  const int mrow = 16 * w + n15;   // A-frag row; wave w owns Mtiles {w, w+4, w+8}
  const int mu = 16 * w + 4 * q;   // C-layout unit base for this lane's 4 regs

  // ---- Wh fragments: rne bf16 (A-frag: row = lane&15, k = q*8+j contiguous) ----
  bf8 whh_[3][2];
  #pragma unroll
  for (int i = 0; i < 3; ++i) {
    #pragma unroll
    for (int kt = 0; kt < 2; ++kt) {
      const float* ph_ = Wh + (size_t)(i * 64 + mrow) * 64 + kt * 32 + q * 8;
      f4 ha = *(const f4*)ph_, hc = *(const f4*)(ph_ + 4);
      bf8 h2;
      #pragma unroll
      for (int j = 0; j < 8; ++j) h2[j] = (short)f2bf_rne((j < 4) ? ha[j] : hc[j - 4]);
      whh_[i][kt] = h2;
    }
  }
  // ---- Wx fragments ----
  bf8 wxh_[3][2];
  if (g >= 1) {
    #pragma unroll
    for (int i = 0; i < 3; ++i) {
      #pragma unroll
      for (int kt = 0; kt < 2; ++kt) {
        const float* px_ = Wx + (size_t)(i * 64 + mrow) * 64 + kt * 32 + q * 8;
        f4 xa = *(const f4*)px_, xc = *(const f4*)(px_ + 4);
        bf8 h1;
        #pragma unroll
        for (int j = 0; j < 8; ++j) h1[j] = (short)f2bf_rne((j < 4) ? xa[j] : xc[j - 4]);
        wxh_[i][kt] = h1;
      }
    }
  } else {
    // layer 0: W0 trunc-hi/lo packed in one K=32 frag. Price (in_dim=4):
    // A j<4 = W0hi[d=j], j>=4 = W0lo[d=j-4]; B = xhi duplicated -> (W0hi+W0lo)@xhi.
    // Sentiment (in_dim=1): A j0,j1 = W0hi, j4,j5 = W0lo; B = {xhi,xlo,0,0,xhi,xlo,..}
    // -> exact W0@x.
    const float* W0 = stack ? W0p : W0s;
    #pragma unroll
    for (int i = 0; i < 3; ++i) {
      bf8 a;
      #pragma unroll
      for (int j = 0; j < 8; ++j) a[j] = 0;
      if (q == 0) {
        if (stack) {
          #pragma unroll
          for (int d = 0; d < 4; ++d) {
            short hi, lo; mk_hilo(W0[(size_t)(i * 64 + mrow) * 4 + d], hi, lo);
            a[d] = hi; a[4 + d] = lo;
          }
        } else {
          short hi, lo; mk_hilo(W0[i * 64 + mrow], hi, lo);
          a[0] = hi; a[1] = hi; a[4] = lo; a[5] = lo;
        }
      }
      wxh_[i][0] = a; wxh_[i][1] = a;
    }
  }

  f4 bR, bZ, bNx, bNh;
  #pragma unroll
  for (int r = 0; r < 4; ++r) {
    bR[r]  = bi[mu + r] + bh[mu + r];
    bZ[r]  = bi[64 + mu + r] + bh[64 + mu + r];
    bNx[r] = bi[128 + mu + r];
    bNh[r] = bh[128 + mu + r];
  }
  f4 h = {0.f, 0.f, 0.f, 0.f};

  // layer-0 per-lane x prefetch (batch row b0+n15)
  const size_t xrow = (size_t)(b0 + n15);
  float px0 = 0.f, px1 = 0.f, px2 = 0.f, px3 = 0.f;
  if (g == 0) {
    if (stack) { f4 t4 = *(const f4*)(xp + xrow * TT * 4); px0 = t4[0]; px1 = t4[1]; px2 = t4[2]; px3 = t4[3]; }
    else       { px0 = xs[xrow * TT]; }
  }

  #pragma unroll 1
  for (int t = 0; t < TT; ++t) {
    waitq(&qdone[g], 4u * (unsigned)t);  // quad peers done step t-1
    bf8 hh0 = *(const bf8*)&hb[g][t & 1][0][n15][q * 8];
    bf8 hh1 = *(const bf8*)&hb[g][t & 1][0][n15][32 + q * 8];
    bf8 hl0 = *(const bf8*)&hb[g][t & 1][1][n15][q * 8];
    bf8 hl1 = *(const bf8*)&hb[g][t & 1][1][n15][32 + q * 8];

    // h-part first (overlaps producer still finishing y(t))
    f4 aR = bR, aZ = bZ, aNx = bNx, aNh = bNh;
    aR  = MFMA16(whh_[0][0], hh0, aR);  aR  = MFMA16(whh_[0][1], hh1, aR);
    aZ  = MFMA16(whh_[1][0], hh0, aZ);  aZ  = MFMA16(whh_[1][1], hh1, aZ);
    aNh = MFMA16(whh_[2][0], hh0, aNh); aNh = MFMA16(whh_[2][1], hh1, aNh);
    aR  = MFMA16(whh_[0][0], hl0, aR);  aR  = MFMA16(whh_[0][1], hl1, aR);
    aZ  = MFMA16(whh_[1][0], hl0, aZ);  aZ  = MFMA16(whh_[1][1], hl1, aZ);
    aNh = MFMA16(whh_[2][0], hl0, aNh); aNh = MFMA16(whh_[2][1], hl1, aNh);

    if (g == 0) {
      // build x B-frag from px, one MFMA per gate
      bf8 xq;
      #pragma unroll
      for (int j = 0; j < 8; ++j) xq[j] = 0;
      if (q == 0) {
        if (stack) {
          short a0 = (short)f2bf_rne(px0), a1 = (short)f2bf_rne(px1);
          short a2 = (short)f2bf_rne(px2), a3 = (short)f2bf_rne(px3);
          xq[0] = a0; xq[1] = a1; xq[2] = a2; xq[3] = a3;
          xq[4] = a0; xq[5] = a1; xq[6] = a2; xq[7] = a3;
        } else {
          unsigned short xh = f2bf_rne(px0);
          float xf = __uint_as_float((unsigned)xh << 16);
          unsigned short xl = f2bf_rne(px0 - xf);
          xq[0] = (short)xh; xq[1] = (short)xl; xq[4] = (short)xh; xq[5] = (short)xl;
        }
      }
      aR  = MFMA16(wxh_[0][0], xq, aR);
      aZ  = MFMA16(wxh_[1][0], xq, aZ);
      aNx = MFMA16(wxh_[2][0], xq, aNx);
      if (t + 1 < TT) {
        if (stack) { f4 t4 = *(const f4*)(xp + (xrow * TT + t + 1) * 4); px0 = t4[0]; px1 = t4[1]; px2 = t4[2]; px3 = t4[3]; }
        else       { px0 = xs[xrow * TT + t + 1]; }
      }
    } else {
      waitq(&qdone[g - 1], 4u * (unsigned)(t + 1));  // y(t) from layer g-1 ready
      bf8 xc0 = *(const bf8*)&yb[g - 1][t & 3][n15][q * 8];
      bf8 xc1 = *(const bf8*)&yb[g - 1][t & 3][n15][32 + q * 8];
      aR  = MFMA16(wxh_[0][0], xc0, aR);  aR  = MFMA16(wxh_[0][1], xc1, aR);
      aZ  = MFMA16(wxh_[1][0], xc0, aZ);  aZ  = MFMA16(wxh_[1][1], xc1, aZ);
      aNx = MFMA16(wxh_[2][0], xc0, aNx); aNx = MFMA16(wxh_[2][1], xc1, aNx);
    }

    #pragma unroll
    for (int r = 0; r < 4; ++r) {
      float rr = sigm(aR[r]);
      float zz = sigm(aZ[r]);
      float nn = tanh_f(aNx[r] + rr * aNh[r]);
      h[r] = nn + zz * (h[r] - nn);
    }

    // hi = rne(h) (also the y value), lo = rne(h - hi)
    us4 hiw, low;
    #pragma unroll
    for (int r = 0; r < 4; ++r) {
      unsigned short hv = f2bf_rne(h[r]);
      hiw[r] = hv;
      float hf = __uint_as_float((unsigned)hv << 16);
      low[r] = f2bf_rne(h[r] - hf);
    }
    *(us4*)&hb[g][(t + 1) & 1][0][n15][mu] = hiw;
    *(us4*)&hb[g][(t + 1) & 1][1][n15][mu] = low;
    if (g < 3) {
      if (t >= 4) waitq(&qdone[g + 1], 4u * (unsigned)(t - 3));  // ring backpressure
      *(us4*)&yb[g][t & 3][n15][mu] = hiw;
    } else if (t == TT - 1) {
      *(f4*)&hlast[((size_t)stack * BB + b0 + n15) * 64 + mu] = h;
    }
    if (lane == 0)
      __hip_atomic_fetch_add(&qdone[g], 1u, __ATOMIC_RELEASE, __HIP_MEMORY_SCOPE_WORKGROUP);
  }
}

// ---------------- FC head ----------------
__global__ __launch_bounds__(128) void head(
    const float* __restrict__ hlast,
    const float* __restrict__ W1, const float* __restrict__ b1,
    const float* __restrict__ g1, const float* __restrict__ be1,
    const float* __restrict__ m1, const float* __restrict__ v1,
    const float* __restrict__ W2, const float* __restrict__ b2,
    const float* __restrict__ g2, const float* __restrict__ be2,
    const float* __restrict__ m2, const float* __restrict__ v2,
    const float* __restrict__ W3, const float* __restrict__ b3,
    float* __restrict__ out) {
  const int b = blockIdx.x;
  const int j = threadIdx.x;
  __shared__ float xin[128];
  __shared__ float y1[128];
  __shared__ float y2[128];
  xin[j] = (j < 64) ? hlast[(size_t)b * 64 + j]
                    : hlast[(size_t)BB * 64 + (size_t)b * 64 + (j - 64)];
  __syncthreads();
  float acc = b1[j];
  #pragma unroll 8
  for (int k = 0; k < 128; ++k) acc = fmaf(W1[j * 128 + k], xin[k], acc);
  float sc = g1[j] * rsqrtf(v1[j] + 1e-5f);
  y1[j] = fmaxf(0.f, (acc - m1[j]) * sc + be1[j]);
  __syncthreads();
  acc = b2[j];
  #pragma unroll 8
  for (int k = 0; k < 128; ++k) acc = fmaf(W2[j * 128 + k], y1[k], acc);
  sc = g2[j] * rsqrtf(v2[j] + 1e-5f);
  y2[j] = fmaxf(0.f, (acc - m2[j]) * sc + be2[j]);
  __syncthreads();
  if (j < 2) {
    float a = b3[j];
    #pragma unroll 8
    for (int k = 0; k < 128; ++k) a = fmaf(W3[j * 128 + k], y2[k], a);
    out[(size_t)b * 2 + j] = a;
  }
}

}  // namespace

extern "C" void kernel_launch(void* const* d_in, const int* in_sizes, int n_in,
                              void* d_out, int out_size, void* d_ws, size_t ws_size,
                              hipStream_t stream) {
  (void)in_sizes; (void)n_in; (void)out_size; (void)ws_size;
  const float* sent   = (const float*)d_in[0];
  const float* price  = (const float*)d_in[1];
  const float* s_Wih0 = (const float*)d_in[2];
  const float* s_Wih  = (const float*)d_in[3];
  const float* s_Whh  = (const float*)d_in[4];
  const float* s_bih  = (const float*)d_in[5];
  const float* s_bhh  = (const float*)d_in[6];
  const float* p_Wih0 = (const float*)d_in[7];
  const float* p_Wih  = (const float*)d_in[8];
  const float* p_Whh  = (const float*)d_in[9];
  const float* p_bih  = (const float*)d_in[10];
  const float* p_bhh  = (const float*)d_in[11];
  const float* fc1_W  = (const float*)d_in[12];
  const float* fc1_b  = (const float*)d_in[13];
  const float* bn1_g  = (const float*)d_in[14];
  const float* bn1_b  = (const float*)d_in[15];
  const float* bn1_m  = (const float*)d_in[16];
  const float* bn1_v  = (const float*)d_in[17];
  const float* fc2_W  = (const float*)d_in[18];
  const float* fc2_b  = (const float*)d_in[19];
  const float* bn2_g  = (const float*)d_in[20];
  const float* bn2_b  = (const float*)d_in[21];
  const float* bn2_m  = (const float*)d_in[22];
  const float* bn2_v  = (const float*)d_in[23];
  const float* fc3_W  = (const float*)d_in[24];
  const float* fc3_b  = (const float*)d_in[25];
  float* out = (float*)d_out;

  float* hlast = (float*)d_ws;  // [2, B, 64] f32

  gru_all<<<dim3(256), dim3(1024), 0, stream>>>(
      sent, price, s_Wih0, p_Wih0, s_Wih, p_Wih, s_Whh, p_Whh,
      s_bih, p_bih, s_bhh, p_bhh, hlast);

  head<<<dim3(BB), dim3(128), 0, stream>>>(
      hlast, fc1_W, fc1_b, bn1_g, bn1_b, bn1_m, bn1_v,
      fc2_W, fc2_b, bn2_g, bn2_b, bn2_m, bn2_v, fc3_W, fc3_b, out);
}

// Round 7
// 419.579 us; speedup vs baseline: 2.0914x; 1.0136x over previous
//
#include <hip/hip_runtime.h>

namespace {

constexpr int BB = 2048;   // batch
constexpr int TT = 256;    // time steps

typedef __attribute__((ext_vector_type(8))) short bf8;          // 8 bf16 (4 VGPR)
typedef __attribute__((ext_vector_type(4))) float f4;           // MFMA acc
typedef __attribute__((ext_vector_type(4))) unsigned short us4;

#define MFMA16(a, b, c) __builtin_amdgcn_mfma_f32_16x16x32_bf16((a), (b), (c), 0, 0, 0)

__device__ __forceinline__ unsigned short f2bf_rne(float f) {
  unsigned int x = __float_as_uint(f);
  return (unsigned short)((x + 0x7fffu + ((x >> 16) & 1u)) >> 16);
}
__device__ __forceinline__ float sigm(float x) {
  return __builtin_amdgcn_rcpf(1.f + __expf(-x));
}
__device__ __forceinline__ float tanh_f(float x) {
  float e = __expf(2.f * x);
  return 1.f - 2.f * __builtin_amdgcn_rcpf(e + 1.f);
}
__device__ __forceinline__ void mk_hilo(float v, short& hi, short& lo) {
  unsigned int u = __float_as_uint(v);
  hi = (short)(u >> 16);
  float r = v - __uint_as_float(u & 0xffff0000u);
  lo = (short)(__float_as_uint(r) >> 16);
}

// ACQUIRE poll of an LDS counter (wave-uniform address).
__device__ __forceinline__ void waitq(const unsigned* c, unsigned tgt) {
  while (__hip_atomic_load(c, __ATOMIC_ACQUIRE, __HIP_MEMORY_SCOPE_WORKGROUP) < tgt)
    __builtin_amdgcn_s_sleep(1);
}

// ============ all 4 GRU layers, free-running pipelined in one block ============
// 1024 threads = 16 waves = 4 quads; quad g = layer g. Sync via LDS sum-counters
// (RELEASE ds_add per wave after writes; ACQUIRE polls). h double-buffered by
// parity; inter-layer y rings depth 4 with backpressure. No __syncthreads in
// the time loop. Numerics: Wh/Wx rne-bf16 hi; h kept as bf16 hi+lo (whh@hl
// compensation) so the recurrence state is ~fp32-accurate.
// __launch_bounds__(1024, 4): 4 waves/EU (exactly one block/CU) -> 128-VGPR
// cap; the default (64) caused per-step spill/remat churn (R6: VALUBusy 63%
// with only ~300 real VALU cycles of work).
__global__ __launch_bounds__(1024, 4) void gru_all(
    const float* __restrict__ xs, const float* __restrict__ xp,
    const float* __restrict__ W0s, const float* __restrict__ W0p,
    const float* __restrict__ Wihs, const float* __restrict__ Wihp,  // [3][192][64]
    const float* __restrict__ Whhs, const float* __restrict__ Whhp,  // [4][192][64]
    const float* __restrict__ bihs, const float* __restrict__ bihp,  // [4][192]
    const float* __restrict__ bhhs, const float* __restrict__ bhhp,
    float* __restrict__ hlast) {
  const int tid = threadIdx.x;
  const int Wv = tid >> 6, lane = tid & 63;
  const int g = Wv >> 2, w = Wv & 3;      // quad (=layer), wave-in-quad
  const int n15 = lane & 15, q = lane >> 4;
  const int blk = blockIdx.x, stack = blk >> 7;
  const int b0 = (blk & 127) * 16;

  const float* Wh = (stack ? Whhp : Whhs) + (size_t)g * 192 * 64;
  const float* bi = (stack ? bihp : bihs) + g * 192;
  const float* bh = (stack ? bhhp : bhhs) + g * 192;
  const float* Wx = (stack ? Wihp : Wihs) + (size_t)(g - 1) * 192 * 64;  // g>=1

  __shared__ unsigned short hb[4][2][2][16][72];  // [g][parity][hi/lo][n][64+8]
  __shared__ unsigned short yb[3][4][16][72];     // [g][ring slot][n][64+8]
  __shared__ unsigned qdone[4];

  for (int e = tid; e < 4 * 2 * 2 * 16 * 72; e += 1024) ((unsigned short*)hb)[e] = 0;
  if (tid < 4) qdone[tid] = 0;
  __syncthreads();  // only barrier in the kernel

  const int mrow = 16 * w + n15;   // A-frag row; wave w owns Mtiles {w, w+4, w+8}
  const int mu = 16 * w + 4 * q;   // C-layout unit base for this lane's 4 regs

  // ---- Wh fragments: rne bf16 (A-frag: row = lane&15, k = q*8+j contiguous) ----
  bf8 whh_[3][2];
  #pragma unroll
  for (int i = 0; i < 3; ++i) {
    #pragma unroll
    for (int kt = 0; kt < 2; ++kt) {
      const float* ph_ = Wh + (size_t)(i * 64 + mrow) * 64 + kt * 32 + q * 8;
      f4 ha = *(const f4*)ph_, hc = *(const f4*)(ph_ + 4);
      bf8 h2;
      #pragma unroll
      for (int j = 0; j < 8; ++j) h2[j] = (short)f2bf_rne((j < 4) ? ha[j] : hc[j - 4]);
      whh_[i][kt] = h2;
    }
  }
  // ---- Wx fragments ----
  bf8 wxh_[3][2];
  if (g >= 1) {
    #pragma unroll
    for (int i = 0; i < 3; ++i) {
      #pragma unroll
      for (int kt = 0; kt < 2; ++kt) {
        const float* px_ = Wx + (size_t)(i * 64 + mrow) * 64 + kt * 32 + q * 8;
        f4 xa = *(const f4*)px_, xc = *(const f4*)(px_ + 4);
        bf8 h1;
        #pragma unroll
        for (int j = 0; j < 8; ++j) h1[j] = (short)f2bf_rne((j < 4) ? xa[j] : xc[j - 4]);
        wxh_[i][kt] = h1;
      }
    }
  } else {
    // layer 0: W0 trunc-hi/lo packed in one K=32 frag. Price (in_dim=4):
    // A j<4 = W0hi[d=j], j>=4 = W0lo[d=j-4]; B = xhi duplicated -> (W0hi+W0lo)@xhi.
    // Sentiment (in_dim=1): A j0,j1 = W0hi, j4,j5 = W0lo; B = {xhi,xlo,0,0,xhi,xlo,..}
    // -> exact W0@x.
    const float* W0 = stack ? W0p : W0s;
    #pragma unroll
    for (int i = 0; i < 3; ++i) {
      bf8 a;
      #pragma unroll
      for (int j = 0; j < 8; ++j) a[j] = 0;
      if (q == 0) {
        if (stack) {
          #pragma unroll
          for (int d = 0; d < 4; ++d) {
            short hi, lo; mk_hilo(W0[(size_t)(i * 64 + mrow) * 4 + d], hi, lo);
            a[d] = hi; a[4 + d] = lo;
          }
        } else {
          short hi, lo; mk_hilo(W0[i * 64 + mrow], hi, lo);
          a[0] = hi; a[1] = hi; a[4] = lo; a[5] = lo;
        }
      }
      wxh_[i][0] = a; wxh_[i][1] = a;
    }
  }

  f4 bR, bZ, bNx, bNh;
  #pragma unroll
  for (int r = 0; r < 4; ++r) {
    bR[r]  = bi[mu + r] + bh[mu + r];
    bZ[r]  = bi[64 + mu + r] + bh[64 + mu + r];
    bNx[r] = bi[128 + mu + r];
    bNh[r] = bh[128 + mu + r];
  }
  f4 h = {0.f, 0.f, 0.f, 0.f};

  // layer-0 per-lane x prefetch (batch row b0+n15)
  const size_t xrow = (size_t)(b0 + n15);
  float px0 = 0.f, px1 = 0.f, px2 = 0.f, px3 = 0.f;
  if (g == 0) {
    if (stack) { f4 t4 = *(const f4*)(xp + xrow * TT * 4); px0 = t4[0]; px1 = t4[1]; px2 = t4[2]; px3 = t4[3]; }
    else       { px0 = xs[xrow * TT]; }
  }

  #pragma unroll 4
  for (int t = 0; t < TT; ++t) {
    waitq(&qdone[g], 4u * (unsigned)t);  // quad peers done step t-1
    bf8 hh0 = *(const bf8*)&hb[g][t & 1][0][n15][q * 8];
    bf8 hh1 = *(const bf8*)&hb[g][t & 1][0][n15][32 + q * 8];
    bf8 hl0 = *(const bf8*)&hb[g][t & 1][1][n15][q * 8];
    bf8 hl1 = *(const bf8*)&hb[g][t & 1][1][n15][32 + q * 8];

    // h-part first (overlaps producer still finishing y(t))
    f4 aR = bR, aZ = bZ, aNx = bNx, aNh = bNh;
    aR  = MFMA16(whh_[0][0], hh0, aR);  aR  = MFMA16(whh_[0][1], hh1, aR);
    aZ  = MFMA16(whh_[1][0], hh0, aZ);  aZ  = MFMA16(whh_[1][1], hh1, aZ);
    aNh = MFMA16(whh_[2][0], hh0, aNh); aNh = MFMA16(whh_[2][1], hh1, aNh);
    aR  = MFMA16(whh_[0][0], hl0, aR);  aR  = MFMA16(whh_[0][1], hl1, aR);
    aZ  = MFMA16(whh_[1][0], hl0, aZ);  aZ  = MFMA16(whh_[1][1], hl1, aZ);
    aNh = MFMA16(whh_[2][0], hl0, aNh); aNh = MFMA16(whh_[2][1], hl1, aNh);

    if (g == 0) {
      // build x B-frag from px, one MFMA per gate
      bf8 xq;
      #pragma unroll
      for (int j = 0; j < 8; ++j) xq[j] = 0;
      if (q == 0) {
        if (stack) {
          short a0 = (short)f2bf_rne(px0), a1 = (short)f2bf_rne(px1);
          short a2 = (short)f2bf_rne(px2), a3 = (short)f2bf_rne(px3);
          xq[0] = a0; xq[1] = a1; xq[2] = a2; xq[3] = a3;
          xq[4] = a0; xq[5] = a1; xq[6] = a2; xq[7] = a3;
        } else {
          unsigned short xh = f2bf_rne(px0);
          float xf = __uint_as_float((unsigned)xh << 16);
          unsigned short xl = f2bf_rne(px0 - xf);
          xq[0] = (short)xh; xq[1] = (short)xl; xq[4] = (short)xh; xq[5] = (short)xl;
        }
      }
      aR  = MFMA16(wxh_[0][0], xq, aR);
      aZ  = MFMA16(wxh_[1][0], xq, aZ);
      aNx = MFMA16(wxh_[2][0], xq, aNx);
      if (t + 1 < TT) {
        if (stack) { f4 t4 = *(const f4*)(xp + (xrow * TT + t + 1) * 4); px0 = t4[0]; px1 = t4[1]; px2 = t4[2]; px3 = t4[3]; }
        else       { px0 = xs[xrow * TT + t + 1]; }
      }
    } else {
      waitq(&qdone[g - 1], 4u * (unsigned)(t + 1));  // y(t) from layer g-1 ready
      bf8 xc0 = *(const bf8*)&yb[g - 1][t & 3][n15][q * 8];
      bf8 xc1 = *(const bf8*)&yb[g - 1][t & 3][n15][32 + q * 8];
      aR  = MFMA16(wxh_[0][0], xc0, aR);  aR  = MFMA16(wxh_[0][1], xc1, aR);
      aZ  = MFMA16(wxh_[1][0], xc0, aZ);  aZ  = MFMA16(wxh_[1][1], xc1, aZ);
      aNx = MFMA16(wxh_[2][0], xc0, aNx); aNx = MFMA16(wxh_[2][1], xc1, aNx);
    }

    #pragma unroll
    for (int r = 0; r < 4; ++r) {
      float rr = sigm(aR[r]);
      float zz = sigm(aZ[r]);
      float nn = tanh_f(aNx[r] + rr * aNh[r]);
      h[r] = nn + zz * (h[r] - nn);
    }

    // hi = rne(h) (also the y value), lo = rne(h - hi)
    us4 hiw, low;
    #pragma unroll
    for (int r = 0; r < 4; ++r) {
      unsigned short hv = f2bf_rne(h[r]);
      hiw[r] = hv;
      float hf = __uint_as_float((unsigned)hv << 16);
      low[r] = f2bf_rne(h[r] - hf);
    }
    *(us4*)&hb[g][(t + 1) & 1][0][n15][mu] = hiw;
    *(us4*)&hb[g][(t + 1) & 1][1][n15][mu] = low;
    if (g < 3) {
      if (t >= 4) waitq(&qdone[g + 1], 4u * (unsigned)(t - 3));  // ring backpressure
      *(us4*)&yb[g][t & 3][n15][mu] = hiw;
    } else if (t == TT - 1) {
      *(f4*)&hlast[((size_t)stack * BB + b0 + n15) * 64 + mu] = h;
    }
    if (lane == 0)
      __hip_atomic_fetch_add(&qdone[g], 1u, __ATOMIC_RELEASE, __HIP_MEMORY_SCOPE_WORKGROUP);
  }
}

// ---------------- FC head ----------------
__global__ __launch_bounds__(128) void head(
    const float* __restrict__ hlast,
    const float* __restrict__ W1, const float* __restrict__ b1,
    const float* __restrict__ g1, const float* __restrict__ be1,
    const float* __restrict__ m1, const float* __restrict__ v1,
    const float* __restrict__ W2, const float* __restrict__ b2,
    const float* __restrict__ g2, const float* __restrict__ be2,
    const float* __restrict__ m2, const float* __restrict__ v2,
    const float* __restrict__ W3, const float* __restrict__ b3,
    float* __restrict__ out) {
  const int b = blockIdx.x;
  const int j = threadIdx.x;
  __shared__ float xin[128];
  __shared__ float y1[128];
  __shared__ float y2[128];
  xin[j] = (j < 64) ? hlast[(size_t)b * 64 + j]
                    : hlast[(size_t)BB * 64 + (size_t)b * 64 + (j - 64)];
  __syncthreads();
  float acc = b1[j];
  #pragma unroll 8
  for (int k = 0; k < 128; ++k) acc = fmaf(W1[j * 128 + k], xin[k], acc);
  float sc = g1[j] * rsqrtf(v1[j] + 1e-5f);
  y1[j] = fmaxf(0.f, (acc - m1[j]) * sc + be1[j]);
  __syncthreads();
  acc = b2[j];
  #pragma unroll 8
  for (int k = 0; k < 128; ++k) acc = fmaf(W2[j * 128 + k], y1[k], acc);
  sc = g2[j] * rsqrtf(v2[j] + 1e-5f);
  y2[j] = fmaxf(0.f, (acc - m2[j]) * sc + be2[j]);
  __syncthreads();
  if (j < 2) {
    float a = b3[j];
    #pragma unroll 8
    for (int k = 0; k < 128; ++k) a = fmaf(W3[j * 128 + k], y2[k], a);
    out[(size_t)b * 2 + j] = a;
  }
}

}  // namespace

extern "C" void kernel_launch(void* const* d_in, const int* in_sizes, int n_in,
                              void* d_out, int out_size, void* d_ws, size_t ws_size,
                              hipStream_t stream) {
  (void)in_sizes; (void)n_in; (void)out_size; (void)ws_size;
  const float* sent   = (const float*)d_in[0];
  const float* price  = (const float*)d_in[1];
  const float* s_Wih0 = (const float*)d_in[2];
  const float* s_Wih  = (const float*)d_in[3];
  const float* s_Whh  = (const float*)d_in[4];
  const float* s_bih  = (const float*)d_in[5];
  const float* s_bhh  = (const float*)d_in[6];
  const float* p_Wih0 = (const float*)d_in[7];
  const float* p_Wih  = (const float*)d_in[8];
  const float* p_Whh  = (const float*)d_in[9];
  const float* p_bih  = (const float*)d_in[10];
  const float* p_bhh  = (const float*)d_in[11];
  const float* fc1_W  = (const float*)d_in[12];
  const float* fc1_b  = (const float*)d_in[13];
  const float* bn1_g  = (const float*)d_in[14];
  const float* bn1_b  = (const float*)d_in[15];
  const float* bn1_m  = (const float*)d_in[16];
  const float* bn1_v  = (const float*)d_in[17];
  const float* fc2_W  = (const float*)d_in[18];
  const float* fc2_b  = (const float*)d_in[19];
  const float* bn2_g  = (const float*)d_in[20];
  const float* bn2_b  = (const float*)d_in[21];
  const float* bn2_m  = (const float*)d_in[22];
  const float* bn2_v  = (const float*)d_in[23];
  const float* fc3_W  = (const float*)d_in[24];
  const float* fc3_b  = (const float*)d_in[25];
  float* out = (float*)d_out;

  float* hlast = (float*)d_ws;  // [2, B, 64] f32

  gru_all<<<dim3(256), dim3(1024), 0, stream>>>(
      sent, price, s_Wih0, p_Wih0, s_Wih, p_Wih, s_Whh, p_Whh,
      s_bih, p_bih, s_bhh, p_bhh, hlast);

  head<<<dim3(BB), dim3(128), 0, stream>>>(
      hlast, fc1_W, fc1_b, bn1_g, bn1_b, bn1_m, bn1_v,
      fc2_W, fc2_b, bn2_g, bn2_b, bn2_m, bn2_v, fc3_W, fc3_b, out);
}

// Round 8
// 401.701 us; speedup vs baseline: 2.1845x; 1.0445x over previous
//
#include <hip/hip_runtime.h>

namespace {

constexpr int BB = 2048;   // batch
constexpr int TT = 256;    // time steps

typedef __attribute__((ext_vector_type(8))) short bf8;          // 8 bf16 (4 VGPR)
typedef __attribute__((ext_vector_type(4))) float f4;           // MFMA acc
typedef __attribute__((ext_vector_type(4))) unsigned short us4;
typedef __attribute__((ext_vector_type(2))) unsigned int u32x2;

#define MFMA16(a, b, c) __builtin_amdgcn_mfma_f32_16x16x32_bf16((a), (b), (c), 0, 0, 0)

__device__ __forceinline__ unsigned short f2bf_rne(float f) {
  unsigned int x = __float_as_uint(f);
  return (unsigned short)((x + 0x7fffu + ((x >> 16) & 1u)) >> 16);
}
__device__ __forceinline__ float sigm(float x) {
  return __builtin_amdgcn_rcpf(1.f + __expf(-x));
}
__device__ __forceinline__ float tanh_f(float x) {
  float e = __expf(2.f * x);
  return 1.f - 2.f * __builtin_amdgcn_rcpf(e + 1.f);
}
__device__ __forceinline__ void mk_hilo(float v, short& hi, short& lo) {
  unsigned int u = __float_as_uint(v);
  hi = (short)(u >> 16);
  float r = v - __uint_as_float(u & 0xffff0000u);
  lo = (short)(__float_as_uint(r) >> 16);
}

// ACQUIRE poll of an LDS counter (wave-uniform address).
__device__ __forceinline__ void waitq(const unsigned* c, unsigned tgt) {
  while (__hip_atomic_load(c, __ATOMIC_ACQUIRE, __HIP_MEMORY_SCOPE_WORKGROUP) < tgt)
    __builtin_amdgcn_s_sleep(1);
}

// ============ all 4 GRU layers, free-running pipelined in one block ============
// 1024 threads = 16 waves = 4 quads; quad g = layer g. Sync via LDS sum-counters.
// h double-buffered by parity; inter-layer y rings depth 4 with backpressure.
// Numerics: Wh/Wx rne-bf16 hi; h kept as bf16 hi+lo (whh@hl compensation).
__global__ __launch_bounds__(1024, 4) void gru_all(
    const float* __restrict__ xs, const float* __restrict__ xp,
    const float* __restrict__ W0s, const float* __restrict__ W0p,
    const float* __restrict__ Wihs, const float* __restrict__ Wihp,  // [3][192][64]
    const float* __restrict__ Whhs, const float* __restrict__ Whhp,  // [4][192][64]
    const float* __restrict__ bihs, const float* __restrict__ bihp,  // [4][192]
    const float* __restrict__ bhhs, const float* __restrict__ bhhp,
    float* __restrict__ hlast) {
  const int tid = threadIdx.x;
  const int Wv = tid >> 6, lane = tid & 63;
  const int g = Wv >> 2, w = Wv & 3;      // quad (=layer), wave-in-quad
  const int n15 = lane & 15, q = lane >> 4;
  const int blk = blockIdx.x, stack = blk >> 7;
  const int b0 = (blk & 127) * 16;

  const float* Wh = (stack ? Whhp : Whhs) + (size_t)g * 192 * 64;
  const float* bi = (stack ? bihp : bihs) + g * 192;
  const float* bh = (stack ? bhhp : bhhs) + g * 192;
  const float* Wx = (stack ? Wihp : Wihs) + (size_t)(g - 1) * 192 * 64;  // g>=1

  __shared__ unsigned short hb[4][2][2][16][72];  // [g][parity][hi/lo][n][64+8]
  __shared__ unsigned short yb[3][4][16][72];     // [g][ring slot][n][64+8]
  __shared__ unsigned qdone[4];

  for (int e = tid; e < 4 * 2 * 2 * 16 * 72; e += 1024) ((unsigned short*)hb)[e] = 0;
  if (tid < 4) qdone[tid] = 0;
  __syncthreads();  // only barrier in the kernel

  const int mrow = 16 * w + n15;   // A-frag row; wave w owns Mtiles {w, w+4, w+8}
  const int mu = 16 * w + 4 * q;   // C-layout unit base for this lane's 4 regs

  // ---- Wh fragments: rne bf16 (A-frag: row = lane&15, k = q*8+j contiguous) ----
  bf8 whh_[3][2];
  #pragma unroll
  for (int i = 0; i < 3; ++i) {
    #pragma unroll
    for (int kt = 0; kt < 2; ++kt) {
      const float* ph_ = Wh + (size_t)(i * 64 + mrow) * 64 + kt * 32 + q * 8;
      f4 ha = *(const f4*)ph_, hc = *(const f4*)(ph_ + 4);
      bf8 h2;
      #pragma unroll
      for (int j = 0; j < 8; ++j) h2[j] = (short)f2bf_rne((j < 4) ? ha[j] : hc[j - 4]);
      whh_[i][kt] = h2;
    }
  }
  // ---- Wx fragments ----
  bf8 wxh_[3][2];
  if (g >= 1) {
    #pragma unroll
    for (int i = 0; i < 3; ++i) {
      #pragma unroll
      for (int kt = 0; kt < 2; ++kt) {
        const float* px_ = Wx + (size_t)(i * 64 + mrow) * 64 + kt * 32 + q * 8;
        f4 xa = *(const f4*)px_, xc = *(const f4*)(px_ + 4);
        bf8 h1;
        #pragma unroll
        for (int j = 0; j < 8; ++j) h1[j] = (short)f2bf_rne((j < 4) ? xa[j] : xc[j - 4]);
        wxh_[i][kt] = h1;
      }
    }
  } else {
    // layer 0: W0 trunc-hi/lo packed in one K=32 frag (see R6 comment).
    const float* W0 = stack ? W0p : W0s;
    #pragma unroll
    for (int i = 0; i < 3; ++i) {
      bf8 a;
      #pragma unroll
      for (int j = 0; j < 8; ++j) a[j] = 0;
      if (q == 0) {
        if (stack) {
          #pragma unroll
          for (int d = 0; d < 4; ++d) {
            short hi, lo; mk_hilo(W0[(size_t)(i * 64 + mrow) * 4 + d], hi, lo);
            a[d] = hi; a[4 + d] = lo;
          }
        } else {
          short hi, lo; mk_hilo(W0[i * 64 + mrow], hi, lo);
          a[0] = hi; a[1] = hi; a[4] = lo; a[5] = lo;
        }
      }
      wxh_[i][0] = a; wxh_[i][1] = a;
    }
  }

  f4 bR, bZ, bNx, bNh;
  #pragma unroll
  for (int r = 0; r < 4; ++r) {
    bR[r]  = bi[mu + r] + bh[mu + r];
    bZ[r]  = bi[64 + mu + r] + bh[64 + mu + r];
    bNx[r] = bi[128 + mu + r];
    bNh[r] = bh[128 + mu + r];
  }
  f4 h = {0.f, 0.f, 0.f, 0.f};

  // layer-0 per-lane x prefetch (batch row b0+n15)
  const size_t xrow = (size_t)(b0 + n15);
  float px0 = 0.f, px1 = 0.f, px2 = 0.f, px3 = 0.f;
  if (g == 0) {
    if (stack) { f4 t4 = *(const f4*)(xp + xrow * TT * 4); px0 = t4[0]; px1 = t4[1]; px2 = t4[2]; px3 = t4[3]; }
    else       { px0 = xs[xrow * TT]; }
  }

// One timestep. P is a compile-time parity literal -> all hb addresses fold
// to base + immediate offset. Both waits hoisted to the top; all 6 ds_reads
// issued together; MFMA cluster under setprio(1).
#define GRU_BODY(P)                                                            \
  {                                                                            \
    waitq(&qdone[g], 4u * (unsigned)tc);                                       \
    if (g >= 1) waitq(&qdone[g - 1], 4u * (unsigned)(tc + 1));                 \
    bf8 hh0 = *(const bf8*)&hb[g][P][0][n15][q * 8];                           \
    bf8 hh1 = *(const bf8*)&hb[g][P][0][n15][32 + q * 8];                      \
    bf8 hl0 = *(const bf8*)&hb[g][P][1][n15][q * 8];                           \
    bf8 hl1 = *(const bf8*)&hb[g][P][1][32 + q * 8 > 0 ? n15 : n15][32 + q * 8]; \
    bf8 xc0 = {}, xc1 = {};                                                    \
    if (g >= 1) {                                                              \
      const unsigned short* yp = &yb[g - 1][tc & 3][n15][q * 8];               \
      xc0 = *(const bf8*)yp;                                                   \
      xc1 = *(const bf8*)(yp + 32);                                            \
    }                                                                          \
    f4 aR = bR, aZ = bZ, aNx = bNx, aNh = bNh;                                 \
    __builtin_amdgcn_s_setprio(1);                                             \
    aR  = MFMA16(whh_[0][0], hh0, aR);  aR  = MFMA16(whh_[0][1], hh1, aR);     \
    aZ  = MFMA16(whh_[1][0], hh0, aZ);  aZ  = MFMA16(whh_[1][1], hh1, aZ);     \
    aNh = MFMA16(whh_[2][0], hh0, aNh); aNh = MFMA16(whh_[2][1], hh1, aNh);    \
    aR  = MFMA16(whh_[0][0], hl0, aR);  aR  = MFMA16(whh_[0][1], hl1, aR);     \
    aZ  = MFMA16(whh_[1][0], hl0, aZ);  aZ  = MFMA16(whh_[1][1], hl1, aZ);     \
    aNh = MFMA16(whh_[2][0], hl0, aNh); aNh = MFMA16(whh_[2][1], hl1, aNh);    \
    if (g == 0) {                                                              \
      bf8 xq;                                                                  \
      _Pragma("unroll") for (int j = 0; j < 8; ++j) xq[j] = 0;                 \
      if (q == 0) {                                                            \
        if (stack) {                                                           \
          short a0 = (short)f2bf_rne(px0), a1 = (short)f2bf_rne(px1);          \
          short a2 = (short)f2bf_rne(px2), a3 = (short)f2bf_rne(px3);          \
          xq[0] = a0; xq[1] = a1; xq[2] = a2; xq[3] = a3;                      \
          xq[4] = a0; xq[5] = a1; xq[6] = a2; xq[7] = a3;                      \
        } else {                                                               \
          unsigned short xh = f2bf_rne(px0);                                   \
          float xf = __uint_as_float((unsigned)xh << 16);                      \
          unsigned short xl = f2bf_rne(px0 - xf);                              \
          xq[0] = (short)xh; xq[1] = (short)xl;                                \
          xq[4] = (short)xh; xq[5] = (short)xl;                                \
        }                                                                      \
      }                                                                        \
      aR  = MFMA16(wxh_[0][0], xq, aR);                                        \
      aZ  = MFMA16(wxh_[1][0], xq, aZ);                                        \
      aNx = MFMA16(wxh_[2][0], xq, aNx);                                       \
      if (tc + 1 < TT) {                                                       \
        if (stack) { f4 t4 = *(const f4*)(xp + (xrow * TT + tc + 1) * 4);      \
                     px0 = t4[0]; px1 = t4[1]; px2 = t4[2]; px3 = t4[3]; }     \
        else       { px0 = xs[xrow * TT + tc + 1]; }                           \
      }                                                                        \
    } else {                                                                   \
      aR  = MFMA16(wxh_[0][0], xc0, aR);  aR  = MFMA16(wxh_[0][1], xc1, aR);   \
      aZ  = MFMA16(wxh_[1][0], xc0, aZ);  aZ  = MFMA16(wxh_[1][1], xc1, aZ);   \
      aNx = MFMA16(wxh_[2][0], xc0, aNx); aNx = MFMA16(wxh_[2][1], xc1, aNx);  \
    }                                                                          \
    __builtin_amdgcn_s_setprio(0);                                             \
    _Pragma("unroll") for (int r = 0; r < 4; ++r) {                            \
      float rr = sigm(aR[r]);                                                  \
      float zz = sigm(aZ[r]);                                                  \
      float nn = tanh_f(aNx[r] + rr * aNh[r]);                                 \
      h[r] = nn + zz * (h[r] - nn);                                            \
    }                                                                          \
    unsigned p01, p23, l01, l23;                                               \
    asm("v_cvt_pk_bf16_f32 %0, %1, %2" : "=v"(p01) : "v"(h[0]), "v"(h[1]));   \
    asm("v_cvt_pk_bf16_f32 %0, %1, %2" : "=v"(p23) : "v"(h[2]), "v"(h[3]));   \
    float r0 = h[0] - __uint_as_float(p01 << 16);                              \
    float r1 = h[1] - __uint_as_float(p01 & 0xffff0000u);                      \
    float r2 = h[2] - __uint_as_float(p23 << 16);                              \
    float r3 = h[3] - __uint_as_float(p23 & 0xffff0000u);                      \
    asm("v_cvt_pk_bf16_f32 %0, %1, %2" : "=v"(l01) : "v"(r0), "v"(r1));       \
    asm("v_cvt_pk_bf16_f32 %0, %1, %2" : "=v"(l23) : "v"(r2), "v"(r3));       \
    u32x2 hiw = {p01, p23}, low = {l01, l23};                                  \
    *(u32x2*)&hb[g][P ^ 1][0][n15][mu] = hiw;                                  \
    *(u32x2*)&hb[g][P ^ 1][1][n15][mu] = low;                                  \
    if (g < 3) {                                                               \
      if (tc >= 4) waitq(&qdone[g + 1], 4u * (unsigned)(tc - 3));              \
      *(u32x2*)&yb[g][tc & 3][n15][mu] = hiw;                                  \
    } else if (tc == TT - 1) {                                                 \
      *(f4*)&hlast[((size_t)stack * BB + b0 + n15) * 64 + mu] = h;             \
    }                                                                          \
    if (lane == 0)                                                             \
      __hip_atomic_fetch_add(&qdone[g], 1u, __ATOMIC_RELEASE,                  \
                             __HIP_MEMORY_SCOPE_WORKGROUP);                    \
  }

  for (int t = 0; t < TT; t += 2) {
    { const int tc = t;     GRU_BODY(0) }
    { const int tc = t + 1; GRU_BODY(1) }
  }
#undef GRU_BODY
}

// ---------------- FC head ----------------
__global__ __launch_bounds__(128) void head(
    const float* __restrict__ hlast,
    const float* __restrict__ W1, const float* __restrict__ b1,
    const float* __restrict__ g1, const float* __restrict__ be1,
    const float* __restrict__ m1, const float* __restrict__ v1,
    const float* __restrict__ W2, const float* __restrict__ b2,
    const float* __restrict__ g2, const float* __restrict__ be2,
    const float* __restrict__ m2, const float* __restrict__ v2,
    const float* __restrict__ W3, const float* __restrict__ b3,
    float* __restrict__ out) {
  const int b = blockIdx.x;
  const int j = threadIdx.x;
  __shared__ float xin[128];
  __shared__ float y1[128];
  __shared__ float y2[128];
  xin[j] = (j < 64) ? hlast[(size_t)b * 64 + j]
                    : hlast[(size_t)BB * 64 + (size_t)b * 64 + (j - 64)];
  __syncthreads();
  float acc = b1[j];
  #pragma unroll 8
  for (int k = 0; k < 128; ++k) acc = fmaf(W1[j * 128 + k], xin[k], acc);
  float sc = g1[j] * rsqrtf(v1[j] + 1e-5f);
  y1[j] = fmaxf(0.f, (acc - m1[j]) * sc + be1[j]);
  __syncthreads();
  acc = b2[j];
  #pragma unroll 8
  for (int k = 0; k < 128; ++k) acc = fmaf(W2[j * 128 + k], y1[k], acc);
  sc = g2[j] * rsqrtf(v2[j] + 1e-5f);
  y2[j] = fmaxf(0.f, (acc - m2[j]) * sc + be2[j]);
  __syncthreads();
  if (j < 2) {
    float a = b3[j];
    #pragma unroll 8
    for (int k = 0; k < 128; ++k) a = fmaf(W3[j * 128 + k], y2[k], a);
    out[(size_t)b * 2 + j] = a;
  }
}

}  // namespace

extern "C" void kernel_launch(void* const* d_in, const int* in_sizes, int n_in,
                              void* d_out, int out_size, void* d_ws, size_t ws_size,
                              hipStream_t stream) {
  (void)in_sizes; (void)n_in; (void)out_size; (void)ws_size;
  const float* sent   = (const float*)d_in[0];
  const float* price  = (const float*)d_in[1];
  const float* s_Wih0 = (const float*)d_in[2];
  const float* s_Wih  = (const float*)d_in[3];
  const float* s_Whh  = (const float*)d_in[4];
  const float* s_bih  = (const float*)d_in[5];
  const float* s_bhh  = (const float*)d_in[6];
  const float* p_Wih0 = (const float*)d_in[7];
  const float* p_Wih  = (const float*)d_in[8];
  const float* p_Whh  = (const float*)d_in[9];
  const float* p_bih  = (const float*)d_in[10];
  const float* p_bhh  = (const float*)d_in[11];
  const float* fc1_W  = (const float*)d_in[12];
  const float* fc1_b  = (const float*)d_in[13];
  const float* bn1_g  = (const float*)d_in[14];
  const float* bn1_b  = (const float*)d_in[15];
  const float* bn1_m  = (const float*)d_in[16];
  const float* bn1_v  = (const float*)d_in[17];
  const float* fc2_W  = (const float*)d_in[18];
  const float* fc2_b  = (const float*)d_in[19];
  const float* bn2_g  = (const float*)d_in[20];
  const float* bn2_b  = (const float*)d_in[21];
  const float* bn2_m  = (const float*)d_in[22];
  const float* bn2_v  = (const float*)d_in[23];
  const float* fc3_W  = (const float*)d_in[24];
  const float* fc3_b  = (const float*)d_in[25];
  float* out = (float*)d_out;

  float* hlast = (float*)d_ws;  // [2, B, 64] f32

  gru_all<<<dim3(256), dim3(1024), 0, stream>>>(
      sent, price, s_Wih0, p_Wih0, s_Wih, p_Wih, s_Whh, p_Whh,
      s_bih, p_bih, s_bhh, p_bhh, hlast);

  head<<<dim3(BB), dim3(128), 0, stream>>>(
      hlast, fc1_W, fc1_b, bn1_g, bn1_b, bn1_m, bn1_v,
      fc2_W, fc2_b, bn2_g, bn2_b, bn2_m, bn2_v, fc3_W, fc3_b, out);
}

// Round 9
// 381.608 us; speedup vs baseline: 2.2995x; 1.0527x over previous
//
#include <hip/hip_runtime.h>

namespace {

constexpr int BB = 2048;   // batch
constexpr int TT = 256;    // time steps

typedef __attribute__((ext_vector_type(8))) short bf8;          // 8 bf16 (4 VGPR)
typedef __attribute__((ext_vector_type(4))) float f4;           // MFMA acc
typedef __attribute__((ext_vector_type(2))) unsigned int u32x2;

#define MFMA16(a, b, c) __builtin_amdgcn_mfma_f32_16x16x32_bf16((a), (b), (c), 0, 0, 0)

__device__ __forceinline__ unsigned short f2bf_rne(float f) {
  unsigned int x = __float_as_uint(f);
  return (unsigned short)((x + 0x7fffu + ((x >> 16) & 1u)) >> 16);
}
__device__ __forceinline__ float sigm(float x) {
  return __builtin_amdgcn_rcpf(1.f + __expf(-x));
}
__device__ __forceinline__ float tanh_f(float x) {
  float e = __expf(2.f * x);
  return 1.f - 2.f * __builtin_amdgcn_rcpf(e + 1.f);
}
__device__ __forceinline__ void mk_hilo(float v, short& hi, short& lo) {
  unsigned int u = __float_as_uint(v);
  hi = (short)(u >> 16);
  float r = v - __uint_as_float(u & 0xffff0000u);
  lo = (short)(__float_as_uint(r) >> 16);
}

// ACQUIRE poll of an LDS counter (wave-uniform address).
__device__ __forceinline__ void waitq(const unsigned* c, unsigned tgt) {
  while (__hip_atomic_load(c, __ATOMIC_ACQUIRE, __HIP_MEMORY_SCOPE_WORKGROUP) < tgt)
    __builtin_amdgcn_s_sleep(1);
}

// ============ all 4 GRU layers, free-running pipelined in one block ============
// 1024 threads = 16 waves = 4 quads; quad g = layer g. Sync via LDS sum-counters.
// h-state ring of 4 slots per layer, FRAGMENT-MAJOR layout [u>>3][n][u&7]:
// reader lane l=q*16+n15 reads 16B at q*256+n15*16 -> every 8-lane group covers
// all 32 banks once = conflict-free (old [n][72] layout was an 8-way conflict,
// 3.46e7 conflict cycles/dispatch). The ring serves BOTH the self h-feedback
// (slot t&3) and the next layer's x input (y(t) = h-state(t+1), slot (t+1)&3).
// Numerics: W rne-bf16; h bf16 hi+lo, lo-compensation on the N gate only
// (R/Z go through sigmoid, gain 0.25 -> dropping their comp adds ~1e-4).
__global__ __launch_bounds__(1024, 4) void gru_all(
    const float* __restrict__ xs, const float* __restrict__ xp,
    const float* __restrict__ W0s, const float* __restrict__ W0p,
    const float* __restrict__ Wihs, const float* __restrict__ Wihp,  // [3][192][64]
    const float* __restrict__ Whhs, const float* __restrict__ Whhp,  // [4][192][64]
    const float* __restrict__ bihs, const float* __restrict__ bihp,  // [4][192]
    const float* __restrict__ bhhs, const float* __restrict__ bhhp,
    float* __restrict__ hlast) {
  const int tid = threadIdx.x;
  const int Wv = tid >> 6, lane = tid & 63;
  const int g = Wv >> 2, w = Wv & 3;      // quad (=layer), wave-in-quad
  const int n15 = lane & 15, q = lane >> 4;
  const int blk = blockIdx.x, stack = blk >> 7;
  const int b0 = (blk & 127) * 16;

  const float* Wh = (stack ? Whhp : Whhs) + (size_t)g * 192 * 64;
  const float* bi = (stack ? bihp : bihs) + g * 192;
  const float* bh = (stack ? bhhp : bhhs) + g * 192;
  const float* Wx = (stack ? Wihp : Wihs) + (size_t)(g - 1) * 192 * 64;  // g>=1

  // [g][slot][hi/lo][frag=u>>3][n][elem=u&7]
  __shared__ unsigned short hb[4][4][2][8][16][8];
  __shared__ unsigned qdone[4];

  for (int e = tid; e < 4 * 4 * 2 * 8 * 16 * 8; e += 1024)
    ((unsigned short*)hb)[e] = 0;
  if (tid < 4) qdone[tid] = 0;
  __syncthreads();  // only barrier in the kernel

  const int mrow = 16 * w + n15;   // A-frag row; wave w owns Mtiles {w, w+4, w+8}
  const int mu = 16 * w + 4 * q;   // C-layout unit base for this lane's 4 regs
  const int fr_w = 2 * w + (q >> 1);  // write frag row
  const int eo_w = (q & 1) * 4;       // write elem offset

  // ---- Wh fragments: rne bf16 (A-frag: row = lane&15, k = q*8+j contiguous) ----
  bf8 whh_[3][2];
  #pragma unroll
  for (int i = 0; i < 3; ++i) {
    #pragma unroll
    for (int kt = 0; kt < 2; ++kt) {
      const float* ph_ = Wh + (size_t)(i * 64 + mrow) * 64 + kt * 32 + q * 8;
      f4 ha = *(const f4*)ph_, hc = *(const f4*)(ph_ + 4);
      bf8 h2;
      #pragma unroll
      for (int j = 0; j < 8; ++j) h2[j] = (short)f2bf_rne((j < 4) ? ha[j] : hc[j - 4]);
      whh_[i][kt] = h2;
    }
  }
  // ---- Wx fragments ----
  bf8 wxh_[3][2];
  if (g >= 1) {
    #pragma unroll
    for (int i = 0; i < 3; ++i) {
      #pragma unroll
      for (int kt = 0; kt < 2; ++kt) {
        const float* px_ = Wx + (size_t)(i * 64 + mrow) * 64 + kt * 32 + q * 8;
        f4 xa = *(const f4*)px_, xc = *(const f4*)(px_ + 4);
        bf8 h1;
        #pragma unroll
        for (int j = 0; j < 8; ++j) h1[j] = (short)f2bf_rne((j < 4) ? xa[j] : xc[j - 4]);
        wxh_[i][kt] = h1;
      }
    }
  } else {
    // layer 0: W0 trunc-hi/lo packed in one K=32 frag. Price (in_dim=4):
    // A j<4 = W0hi[d=j], j>=4 = W0lo[d=j-4]; B = xhi duplicated.
    // Sentiment: A j0,j1 = W0hi, j4,j5 = W0lo; B = {xhi,xlo,..} -> exact W0@x.
    const float* W0 = stack ? W0p : W0s;
    #pragma unroll
    for (int i = 0; i < 3; ++i) {
      bf8 a;
      #pragma unroll
      for (int j = 0; j < 8; ++j) a[j] = 0;
      if (q == 0) {
        if (stack) {
          #pragma unroll
          for (int d = 0; d < 4; ++d) {
            short hi, lo; mk_hilo(W0[(size_t)(i * 64 + mrow) * 4 + d], hi, lo);
            a[d] = hi; a[4 + d] = lo;
          }
        } else {
          short hi, lo; mk_hilo(W0[i * 64 + mrow], hi, lo);
          a[0] = hi; a[1] = hi; a[4] = lo; a[5] = lo;
        }
      }
      wxh_[i][0] = a; wxh_[i][1] = a;
    }
  }

  f4 bR, bZ, bNx, bNh;
  #pragma unroll
  for (int r = 0; r < 4; ++r) {
    bR[r]  = bi[mu + r] + bh[mu + r];
    bZ[r]  = bi[64 + mu + r] + bh[64 + mu + r];
    bNx[r] = bi[128 + mu + r];
    bNh[r] = bh[128 + mu + r];
  }
  f4 h = {0.f, 0.f, 0.f, 0.f};

  // layer-0 per-lane x prefetch (batch row b0+n15)
  const size_t xrow = (size_t)(b0 + n15);
  float px0 = 0.f, px1 = 0.f, px2 = 0.f, px3 = 0.f;
  if (g == 0) {
    if (stack) { f4 t4 = *(const f4*)(xp + xrow * TT * 4); px0 = t4[0]; px1 = t4[1]; px2 = t4[2]; px3 = t4[3]; }
    else       { px0 = xs[xrow * TT]; }
  }

// One timestep; S is a compile-time ring-slot literal -> all LDS addresses
// fold to base + immediate offset. Waits hoisted; MFMA under setprio(1).
#define GRU_BODY(S)                                                            \
  {                                                                            \
    constexpr int SW = (S + 1) & 3;                                            \
    waitq(&qdone[g], 4u * (unsigned)tc);                                       \
    if (g >= 1) waitq(&qdone[g - 1], 4u * (unsigned)(tc + 1));                 \
    bf8 hh0 = *(const bf8*)&hb[g][S][0][q][n15][0];                            \
    bf8 hh1 = *(const bf8*)&hb[g][S][0][4 + q][n15][0];                        \
    bf8 hl0 = *(const bf8*)&hb[g][S][1][q][n15][0];                            \
    bf8 hl1 = *(const bf8*)&hb[g][S][1][4 + q][n15][0];                        \
    bf8 xc0 = {}, xc1 = {};                                                    \
    if (g >= 1) {                                                              \
      xc0 = *(const bf8*)&hb[g - 1][SW][0][q][n15][0];                         \
      xc1 = *(const bf8*)&hb[g - 1][SW][0][4 + q][n15][0];                     \
    }                                                                          \
    f4 aR = bR, aZ = bZ, aNx = bNx, aNh = bNh;                                 \
    __builtin_amdgcn_s_setprio(1);                                             \
    aR  = MFMA16(whh_[0][0], hh0, aR);  aR  = MFMA16(whh_[0][1], hh1, aR);     \
    aZ  = MFMA16(whh_[1][0], hh0, aZ);  aZ  = MFMA16(whh_[1][1], hh1, aZ);     \
    aNh = MFMA16(whh_[2][0], hh0, aNh); aNh = MFMA16(whh_[2][1], hh1, aNh);    \
    aNh = MFMA16(whh_[2][0], hl0, aNh); aNh = MFMA16(whh_[2][1], hl1, aNh);    \
    if (g == 0) {                                                              \
      bf8 xq;                                                                  \
      _Pragma("unroll") for (int j = 0; j < 8; ++j) xq[j] = 0;                 \
      if (q == 0) {                                                            \
        if (stack) {                                                           \
          short a0 = (short)f2bf_rne(px0), a1 = (short)f2bf_rne(px1);          \
          short a2 = (short)f2bf_rne(px2), a3 = (short)f2bf_rne(px3);          \
          xq[0] = a0; xq[1] = a1; xq[2] = a2; xq[3] = a3;                      \
          xq[4] = a0; xq[5] = a1; xq[6] = a2; xq[7] = a3;                      \
        } else {                                                               \
          unsigned short xh = f2bf_rne(px0);                                   \
          float xf = __uint_as_float((unsigned)xh << 16);                      \
          unsigned short xl = f2bf_rne(px0 - xf);                              \
          xq[0] = (short)xh; xq[1] = (short)xl;                                \
          xq[4] = (short)xh; xq[5] = (short)xl;                                \
        }                                                                      \
      }                                                                        \
      aR  = MFMA16(wxh_[0][0], xq, aR);                                        \
      aZ  = MFMA16(wxh_[1][0], xq, aZ);                                        \
      aNx = MFMA16(wxh_[2][0], xq, aNx);                                       \
      if (tc + 1 < TT) {                                                       \
        if (stack) { f4 t4 = *(const f4*)(xp + (xrow * TT + tc + 1) * 4);      \
                     px0 = t4[0]; px1 = t4[1]; px2 = t4[2]; px3 = t4[3]; }     \
        else       { px0 = xs[xrow * TT + tc + 1]; }                           \
      }                                                                        \
    } else {                                                                   \
      aR  = MFMA16(wxh_[0][0], xc0, aR);  aR  = MFMA16(wxh_[0][1], xc1, aR);   \
      aZ  = MFMA16(wxh_[1][0], xc0, aZ);  aZ  = MFMA16(wxh_[1][1], xc1, aZ);   \
      aNx = MFMA16(wxh_[2][0], xc0, aNx); aNx = MFMA16(wxh_[2][1], xc1, aNx);  \
    }                                                                          \
    __builtin_amdgcn_s_setprio(0);                                             \
    _Pragma("unroll") for (int r = 0; r < 4; ++r) {                            \
      float rr = sigm(aR[r]);                                                  \
      float zz = sigm(aZ[r]);                                                  \
      float nn = tanh_f(aNx[r] + rr * aNh[r]);                                 \
      h[r] = nn + zz * (h[r] - nn);                                            \
    }                                                                          \
    unsigned p01, p23, l01, l23;                                               \
    asm("v_cvt_pk_bf16_f32 %0, %1, %2" : "=v"(p01) : "v"(h[0]), "v"(h[1]));   \
    asm("v_cvt_pk_bf16_f32 %0, %1, %2" : "=v"(p23) : "v"(h[2]), "v"(h[3]));   \
    float r0 = h[0] - __uint_as_float(p01 << 16);                              \
    float r1 = h[1] - __uint_as_float(p01 & 0xffff0000u);                      \
    float r2 = h[2] - __uint_as_float(p23 << 16);                              \
    float r3 = h[3] - __uint_as_float(p23 & 0xffff0000u);                      \
    asm("v_cvt_pk_bf16_f32 %0, %1, %2" : "=v"(l01) : "v"(r0), "v"(r1));       \
    asm("v_cvt_pk_bf16_f32 %0, %1, %2" : "=v"(l23) : "v"(r2), "v"(r3));       \
    u32x2 hiw = {p01, p23}, low = {l01, l23};                                  \
    if (g < 3 && tc >= 4) waitq(&qdone[g + 1], 4u * (unsigned)(tc - 3));       \
    *(u32x2*)&hb[g][SW][0][fr_w][n15][eo_w] = hiw;                             \
    *(u32x2*)&hb[g][SW][1][fr_w][n15][eo_w] = low;                             \
    if (g == 3 && tc == TT - 1)                                                \
      *(f4*)&hlast[((size_t)stack * BB + b0 + n15) * 64 + mu] = h;             \
    if (lane == 0)                                                             \
      __hip_atomic_fetch_add(&qdone[g], 1u, __ATOMIC_RELEASE,                  \
                             __HIP_MEMORY_SCOPE_WORKGROUP);                    \
  }

  for (int t = 0; t < TT; t += 4) {
    { const int tc = t;     GRU_BODY(0) }
    { const int tc = t + 1; GRU_BODY(1) }
    { const int tc = t + 2; GRU_BODY(2) }
    { const int tc = t + 3; GRU_BODY(3) }
  }
#undef GRU_BODY
}

// ---------------- FC head ----------------
__global__ __launch_bounds__(128) void head(
    const float* __restrict__ hlast,
    const float* __restrict__ W1, const float* __restrict__ b1,
    const float* __restrict__ g1, const float* __restrict__ be1,
    const float* __restrict__ m1, const float* __restrict__ v1,
    const float* __restrict__ W2, const float* __restrict__ b2,
    const float* __restrict__ g2, const float* __restrict__ be2,
    const float* __restrict__ m2, const float* __restrict__ v2,
    const float* __restrict__ W3, const float* __restrict__ b3,
    float* __restrict__ out) {
  const int b = blockIdx.x;
  const int j = threadIdx.x;
  __shared__ float xin[128];
  __shared__ float y1[128];
  __shared__ float y2[128];
  xin[j] = (j < 64) ? hlast[(size_t)b * 64 + j]
                    : hlast[(size_t)BB * 64 + (size_t)b * 64 + (j - 64)];
  __syncthreads();
  float acc = b1[j];
  #pragma unroll 8
  for (int k = 0; k < 128; ++k) acc = fmaf(W1[j * 128 + k], xin[k], acc);
  float sc = g1[j] * rsqrtf(v1[j] + 1e-5f);
  y1[j] = fmaxf(0.f, (acc - m1[j]) * sc + be1[j]);
  __syncthreads();
  acc = b2[j];
  #pragma unroll 8
  for (int k = 0; k < 128; ++k) acc = fmaf(W2[j * 128 + k], y1[k], acc);
  sc = g2[j] * rsqrtf(v2[j] + 1e-5f);
  y2[j] = fmaxf(0.f, (acc - m2[j]) * sc + be2[j]);
  __syncthreads();
  if (j < 2) {
    float a = b3[j];
    #pragma unroll 8
    for (int k = 0; k < 128; ++k) a = fmaf(W3[j * 128 + k], y2[k], a);
    out[(size_t)b * 2 + j] = a;
  }
}

}  // namespace

extern "C" void kernel_launch(void* const* d_in, const int* in_sizes, int n_in,
                              void* d_out, int out_size, void* d_ws, size_t ws_size,
                              hipStream_t stream) {
  (void)in_sizes; (void)n_in; (void)out_size; (void)ws_size;
  const float* sent   = (const float*)d_in[0];
  const float* price  = (const float*)d_in[1];
  const float* s_Wih0 = (const float*)d_in[2];
  const float* s_Wih  = (const float*)d_in[3];
  const float* s_Whh  = (const float*)d_in[4];
  const float* s_bih  = (const float*)d_in[5];
  const float* s_bhh  = (const float*)d_in[6];
  const float* p_Wih0 = (const float*)d_in[7];
  const float* p_Wih  = (const float*)d_in[8];
  const float* p_Whh  = (const float*)d_in[9];
  const float* p_bih  = (const float*)d_in[10];
  const float* p_bhh  = (const float*)d_in[11];
  const float* fc1_W  = (const float*)d_in[12];
  const float* fc1_b  = (const float*)d_in[13];
  const float* bn1_g  = (const float*)d_in[14];
  const float* bn1_b  = (const float*)d_in[15];
  const float* bn1_m  = (const float*)d_in[16];
  const float* bn1_v  = (const float*)d_in[17];
  const float* fc2_W  = (const float*)d_in[18];
  const float* fc2_b  = (const float*)d_in[19];
  const float* bn2_g  = (const float*)d_in[20];
  const float* bn2_b  = (const float*)d_in[21];
  const float* bn2_m  = (const float*)d_in[22];
  const float* bn2_v  = (const float*)d_in[23];
  const float* fc3_W  = (const float*)d_in[24];
  const float* fc3_b  = (const float*)d_in[25];
  float* out = (float*)d_out;

  float* hlast = (float*)d_ws;  // [2, B, 64] f32

  gru_all<<<dim3(256), dim3(1024), 0, stream>>>(
      sent, price, s_Wih0, p_Wih0, s_Wih, p_Wih, s_Whh, p_Whh,
      s_bih, p_bih, s_bhh, p_bhh, hlast);

  head<<<dim3(BB), dim3(128), 0, stream>>>(
      hlast, fc1_W, fc1_b, bn1_g, bn1_b, bn1_m, bn1_v,
      fc2_W, fc2_b, bn2_g, bn2_b, bn2_m, bn2_v, fc3_W, fc3_b, out);
}

// Round 10
// 319.602 us; speedup vs baseline: 2.7456x; 1.1940x over previous
//
#include <hip/hip_runtime.h>

namespace {

constexpr int BB = 2048;   // batch
constexpr int TT = 256;    // time steps
constexpr float L2E = 1.4426950408889634f;  // log2(e)

typedef __attribute__((ext_vector_type(8))) short bf8;          // 8 bf16 (4 VGPR)
typedef __attribute__((ext_vector_type(4))) float f4;           // MFMA acc
typedef __attribute__((ext_vector_type(2))) unsigned int u32x2;

#define MFMA16(a, b, c) __builtin_amdgcn_mfma_f32_16x16x32_bf16((a), (b), (c), 0, 0, 0)

__device__ __forceinline__ unsigned short f2bf_rne(float f) {
  unsigned int x = __float_as_uint(f);
  return (unsigned short)((x + 0x7fffu + ((x >> 16) & 1u)) >> 16);
}
// pre-scaled gates: y = log2e * x  ->  sigmoid(x) = 1/(1+2^-y)
__device__ __forceinline__ float sigm2(float y) {
  return __builtin_amdgcn_rcpf(1.f + __builtin_amdgcn_exp2f(-y));
}
// pre-scaled: y = 2*log2e * x  ->  tanh(x) = 1 - 2/(2^y + 1)
__device__ __forceinline__ float tanh2(float y) {
  return 1.f - 2.f * __builtin_amdgcn_rcpf(__builtin_amdgcn_exp2f(y) + 1.f);
}
__device__ __forceinline__ void mk_hilo(float v, short& hi, short& lo) {
  unsigned int u = __float_as_uint(v);
  hi = (short)(u >> 16);
  float r = v - __uint_as_float(u & 0xffff0000u);
  lo = (short)(__float_as_uint(r) >> 16);
}

// ACQUIRE poll of an LDS counter (wave-uniform address). Tight spin: poll
// granularity = ds_read latency (~120cy), no s_sleep quantization.
__device__ __forceinline__ void waitq(const unsigned* c, unsigned tgt) {
  while (__hip_atomic_load(c, __ATOMIC_ACQUIRE, __HIP_MEMORY_SCOPE_WORKGROUP) < tgt) {}
}

// ============ all 4 GRU layers, free-running pipelined in one block ============
// 1024 threads = 16 waves = 4 quads; quad g = layer g. Sync via LDS sum-counters.
// h-state ring of 4 slots per layer, fragment-major [u>>3][n][u&7] (conflict-free
// b128 reads). Ring serves both self h-feedback (slot t&3) and next layer's x
// (slot (t+1)&3). Numerics: W/b pre-scaled by log2e (R,Z) / 2log2e (N) so gates
// use raw v_exp_f32; h feedback is single rne-bf16 (h itself stays fp32 in regs;
// y path was always hi-only and absmax sat at 2^-9 across R2-R9).
__global__ __launch_bounds__(1024, 4) void gru_all(
    const float* __restrict__ xs, const float* __restrict__ xp,
    const float* __restrict__ W0s, const float* __restrict__ W0p,
    const float* __restrict__ Wihs, const float* __restrict__ Wihp,  // [3][192][64]
    const float* __restrict__ Whhs, const float* __restrict__ Whhp,  // [4][192][64]
    const float* __restrict__ bihs, const float* __restrict__ bihp,  // [4][192]
    const float* __restrict__ bhhs, const float* __restrict__ bhhp,
    float* __restrict__ hlast) {
  const int tid = threadIdx.x;
  const int Wv = tid >> 6, lane = tid & 63;
  const int g = Wv >> 2, w = Wv & 3;      // quad (=layer), wave-in-quad
  const int n15 = lane & 15, q = lane >> 4;
  const int blk = blockIdx.x, stack = blk >> 7;
  const int b0 = (blk & 127) * 16;

  const float* Wh = (stack ? Whhp : Whhs) + (size_t)g * 192 * 64;
  const float* bi = (stack ? bihp : bihs) + g * 192;
  const float* bh = (stack ? bhhp : bhhs) + g * 192;
  const float* Wx = (stack ? Wihp : Wihs) + (size_t)(g - 1) * 192 * 64;  // g>=1

  // [g][slot][frag=u>>3][n][elem=u&7]
  __shared__ unsigned short hb[4][4][8][16][8];
  __shared__ unsigned qdone[4];

  for (int e = tid; e < 4 * 4 * 8 * 16 * 8; e += 1024)
    ((unsigned short*)hb)[e] = 0;
  if (tid < 4) qdone[tid] = 0;
  __syncthreads();  // only barrier in the kernel

  const int mrow = 16 * w + n15;   // A-frag row; wave w owns Mtiles {w, w+4, w+8}
  const int mu = 16 * w + 4 * q;   // C-layout unit base for this lane's 4 regs
  const int fr_w = 2 * w + (q >> 1);  // write frag row
  const int eo_w = (q & 1) * 4;       // write elem offset

  // per-gate pre-scale: R,Z by log2e; N by 2*log2e
  const float gsc[3] = {L2E, L2E, 2.f * L2E};

  // ---- Wh fragments: rne bf16 of (scale * W) ----
  bf8 whh_[3][2];
  #pragma unroll
  for (int i = 0; i < 3; ++i) {
    #pragma unroll
    for (int kt = 0; kt < 2; ++kt) {
      const float* ph_ = Wh + (size_t)(i * 64 + mrow) * 64 + kt * 32 + q * 8;
      f4 ha = *(const f4*)ph_, hc = *(const f4*)(ph_ + 4);
      bf8 h2;
      #pragma unroll
      for (int j = 0; j < 8; ++j)
        h2[j] = (short)f2bf_rne(gsc[i] * ((j < 4) ? ha[j] : hc[j - 4]));
      whh_[i][kt] = h2;
    }
  }
  // ---- Wx fragments ----
  bf8 wxh_[3][2];
  if (g >= 1) {
    #pragma unroll
    for (int i = 0; i < 3; ++i) {
      #pragma unroll
      for (int kt = 0; kt < 2; ++kt) {
        const float* px_ = Wx + (size_t)(i * 64 + mrow) * 64 + kt * 32 + q * 8;
        f4 xa = *(const f4*)px_, xc = *(const f4*)(px_ + 4);
        bf8 h1;
        #pragma unroll
        for (int j = 0; j < 8; ++j)
          h1[j] = (short)f2bf_rne(gsc[i] * ((j < 4) ? xa[j] : xc[j - 4]));
        wxh_[i][kt] = h1;
      }
    }
  } else {
    // layer 0: scaled W0 trunc-hi/lo packed in one K=32 frag (see R6 comment).
    const float* W0 = stack ? W0p : W0s;
    #pragma unroll
    for (int i = 0; i < 3; ++i) {
      bf8 a;
      #pragma unroll
      for (int j = 0; j < 8; ++j) a[j] = 0;
      if (q == 0) {
        if (stack) {
          #pragma unroll
          for (int d = 0; d < 4; ++d) {
            short hi, lo;
            mk_hilo(gsc[i] * W0[(size_t)(i * 64 + mrow) * 4 + d], hi, lo);
            a[d] = hi; a[4 + d] = lo;
          }
        } else {
          short hi, lo; mk_hilo(gsc[i] * W0[i * 64 + mrow], hi, lo);
          a[0] = hi; a[1] = hi; a[4] = lo; a[5] = lo;
        }
      }
      wxh_[i][0] = a; wxh_[i][1] = a;
    }
  }

  f4 bR, bZ, bNx, bNh;
  #pragma unroll
  for (int r = 0; r < 4; ++r) {
    bR[r]  = L2E * (bi[mu + r] + bh[mu + r]);
    bZ[r]  = L2E * (bi[64 + mu + r] + bh[64 + mu + r]);
    bNx[r] = 2.f * L2E * bi[128 + mu + r];
    bNh[r] = 2.f * L2E * bh[128 + mu + r];
  }
  f4 h = {0.f, 0.f, 0.f, 0.f};

  // layer-0 per-lane x prefetch (batch row b0+n15)
  const size_t xrow = (size_t)(b0 + n15);
  float px0 = 0.f, px1 = 0.f, px2 = 0.f, px3 = 0.f;
  if (g == 0) {
    if (stack) { f4 t4 = *(const f4*)(xp + xrow * TT * 4); px0 = t4[0]; px1 = t4[1]; px2 = t4[2]; px3 = t4[3]; }
    else       { px0 = xs[xrow * TT]; }
  }

// One timestep; S is a compile-time ring-slot literal -> all LDS addresses
// fold to base + immediate offset. Waits hoisted; MFMA under setprio(1).
#define GRU_BODY(S)                                                            \
  {                                                                            \
    constexpr int SW = (S + 1) & 3;                                            \
    waitq(&qdone[g], 4u * (unsigned)tc);                                       \
    if (g >= 1) waitq(&qdone[g - 1], 4u * (unsigned)(tc + 1));                 \
    bf8 hh0 = *(const bf8*)&hb[g][S][q][n15][0];                               \
    bf8 hh1 = *(const bf8*)&hb[g][S][4 + q][n15][0];                           \
    bf8 xc0 = {}, xc1 = {};                                                    \
    if (g >= 1) {                                                              \
      xc0 = *(const bf8*)&hb[g - 1][SW][q][n15][0];                            \
      xc1 = *(const bf8*)&hb[g - 1][SW][4 + q][n15][0];                        \
    }                                                                          \
    f4 aR = bR, aZ = bZ, aNx = bNx, aNh = bNh;                                 \
    __builtin_amdgcn_s_setprio(1);                                             \
    aR  = MFMA16(whh_[0][0], hh0, aR);  aR  = MFMA16(whh_[0][1], hh1, aR);     \
    aZ  = MFMA16(whh_[1][0], hh0, aZ);  aZ  = MFMA16(whh_[1][1], hh1, aZ);     \
    aNh = MFMA16(whh_[2][0], hh0, aNh); aNh = MFMA16(whh_[2][1], hh1, aNh);    \
    if (g == 0) {                                                              \
      bf8 xq;                                                                  \
      _Pragma("unroll") for (int j = 0; j < 8; ++j) xq[j] = 0;                 \
      if (q == 0) {                                                            \
        if (stack) {                                                           \
          short a0 = (short)f2bf_rne(px0), a1 = (short)f2bf_rne(px1);          \
          short a2 = (short)f2bf_rne(px2), a3 = (short)f2bf_rne(px3);          \
          xq[0] = a0; xq[1] = a1; xq[2] = a2; xq[3] = a3;                      \
          xq[4] = a0; xq[5] = a1; xq[6] = a2; xq[7] = a3;                      \
        } else {                                                               \
          unsigned short xh = f2bf_rne(px0);                                   \
          float xf = __uint_as_float((unsigned)xh << 16);                      \
          unsigned short xl = f2bf_rne(px0 - xf);                              \
          xq[0] = (short)xh; xq[1] = (short)xl;                                \
          xq[4] = (short)xh; xq[5] = (short)xl;                                \
        }                                                                      \
      }                                                                        \
      aR  = MFMA16(wxh_[0][0], xq, aR);                                        \
      aZ  = MFMA16(wxh_[1][0], xq, aZ);                                        \
      aNx = MFMA16(wxh_[2][0], xq, aNx);                                       \
      if (tc + 1 < TT) {                                                       \
        if (stack) { f4 t4 = *(const f4*)(xp + (xrow * TT + tc + 1) * 4);      \
                     px0 = t4[0]; px1 = t4[1]; px2 = t4[2]; px3 = t4[3]; }     \
        else       { px0 = xs[xrow * TT + tc + 1]; }                           \
      }                                                                        \
    } else {                                                                   \
      aR  = MFMA16(wxh_[0][0], xc0, aR);  aR  = MFMA16(wxh_[0][1], xc1, aR);   \
      aZ  = MFMA16(wxh_[1][0], xc0, aZ);  aZ  = MFMA16(wxh_[1][1], xc1, aZ);   \
      aNx = MFMA16(wxh_[2][0], xc0, aNx); aNx = MFMA16(wxh_[2][1], xc1, aNx);  \
    }                                                                          \
    __builtin_amdgcn_s_setprio(0);                                             \
    _Pragma("unroll") for (int r = 0; r < 4; ++r) {                            \
      float rr = sigm2(aR[r]);                                                 \
      float zz = sigm2(aZ[r]);                                                 \
      float nn = tanh2(aNx[r] + rr * aNh[r]);                                  \
      h[r] = nn + zz * (h[r] - nn);                                            \
    }                                                                          \
    unsigned p01, p23;                                                         \
    asm("v_cvt_pk_bf16_f32 %0, %1, %2" : "=v"(p01) : "v"(h[0]), "v"(h[1]));   \
    asm("v_cvt_pk_bf16_f32 %0, %1, %2" : "=v"(p23) : "v"(h[2]), "v"(h[3]));   \
    u32x2 hiw = {p01, p23};                                                    \
    if (g < 3 && tc >= 4) waitq(&qdone[g + 1], 4u * (unsigned)(tc - 3));       \
    *(u32x2*)&hb[g][SW][fr_w][n15][eo_w] = hiw;                                \
    if (g == 3 && tc == TT - 1)                                                \
      *(f4*)&hlast[((size_t)stack * BB + b0 + n15) * 64 + mu] = h;             \
    if (lane == 0)                                                             \
      __hip_atomic_fetch_add(&qdone[g], 1u, __ATOMIC_RELEASE,                  \
                             __HIP_MEMORY_SCOPE_WORKGROUP);                    \
  }

  for (int t = 0; t < TT; t += 4) {
    { const int tc = t;     GRU_BODY(0) }
    { const int tc = t + 1; GRU_BODY(1) }
    { const int tc = t + 2; GRU_BODY(2) }
    { const int tc = t + 3; GRU_BODY(3) }
  }
#undef GRU_BODY
}

// ---------------- FC head ----------------
__global__ __launch_bounds__(128) void head(
    const float* __restrict__ hlast,
    const float* __restrict__ W1, const float* __restrict__ b1,
    const float* __restrict__ g1, const float* __restrict__ be1,
    const float* __restrict__ m1, const float* __restrict__ v1,
    const float* __restrict__ W2, const float* __restrict__ b2,
    const float* __restrict__ g2, const float* __restrict__ be2,
    const float* __restrict__ m2, const float* __restrict__ v2,
    const float* __restrict__ W3, const float* __restrict__ b3,
    float* __restrict__ out) {
  const int b = blockIdx.x;
  const int j = threadIdx.x;
  __shared__ float xin[128];
  __shared__ float y1[128];
  __shared__ float y2[128];
  xin[j] = (j < 64) ? hlast[(size_t)b * 64 + j]
                    : hlast[(size_t)BB * 64 + (size_t)b * 64 + (j - 64)];
  __syncthreads();
  float acc = b1[j];
  #pragma unroll 8
  for (int k = 0; k < 128; ++k) acc = fmaf(W1[j * 128 + k], xin[k], acc);
  float sc = g1[j] * rsqrtf(v1[j] + 1e-5f);
  y1[j] = fmaxf(0.f, (acc - m1[j]) * sc + be1[j]);
  __syncthreads();
  acc = b2[j];
  #pragma unroll 8
  for (int k = 0; k < 128; ++k) acc = fmaf(W2[j * 128 + k], y1[k], acc);
  sc = g2[j] * rsqrtf(v2[j] + 1e-5f);
  y2[j] = fmaxf(0.f, (acc - m2[j]) * sc + be2[j]);
  __syncthreads();
  if (j < 2) {
    float a = b3[j];
    #pragma unroll 8
    for (int k = 0; k < 128; ++k) a = fmaf(W3[j * 128 + k], y2[k], a);
    out[(size_t)b * 2 + j] = a;
  }
}

}  // namespace

extern "C" void kernel_launch(void* const* d_in, const int* in_sizes, int n_in,
                              void* d_out, int out_size, void* d_ws, size_t ws_size,
                              hipStream_t stream) {
  (void)in_sizes; (void)n_in; (void)out_size; (void)ws_size;
  const float* sent   = (const float*)d_in[0];
  const float* price  = (const float*)d_in[1];
  const float* s_Wih0 = (const float*)d_in[2];
  const float* s_Wih  = (const float*)d_in[3];
  const float* s_Whh  = (const float*)d_in[4];
  const float* s_bih  = (const float*)d_in[5];
  const float* s_bhh  = (const float*)d_in[6];
  const float* p_Wih0 = (const float*)d_in[7];
  const float* p_Wih  = (const float*)d_in[8];
  const float* p_Whh  = (const float*)d_in[9];
  const float* p_bih  = (const float*)d_in[10];
  const float* p_bhh  = (const float*)d_in[11];
  const float* fc1_W  = (const float*)d_in[12];
  const float* fc1_b  = (const float*)d_in[13];
  const float* bn1_g  = (const float*)d_in[14];
  const float* bn1_b  = (const float*)d_in[15];
  const float* bn1_m  = (const float*)d_in[16];
  const float* bn1_v  = (const float*)d_in[17];
  const float* fc2_W  = (const float*)d_in[18];
  const float* fc2_b  = (const float*)d_in[19];
  const float* bn2_g  = (const float*)d_in[20];
  const float* bn2_b  = (const float*)d_in[21];
  const float* bn2_m  = (const float*)d_in[22];
  const float* bn2_v  = (const float*)d_in[23];
  const float* fc3_W  = (const float*)d_in[24];
  const float* fc3_b  = (const float*)d_in[25];
  float* out = (float*)d_out;

  float* hlast = (float*)d_ws;  // [2, B, 64] f32

  gru_all<<<dim3(256), dim3(1024), 0, stream>>>(
      sent, price, s_Wih0, p_Wih0, s_Wih, p_Wih, s_Whh, p_Whh,
      s_bih, p_bih, s_bhh, p_bhh, hlast);

  head<<<dim3(BB), dim3(128), 0, stream>>>(
      hlast, fc1_W, fc1_b, bn1_g, bn1_b, bn1_m, bn1_v,
      fc2_W, fc2_b, bn2_g, bn2_b, bn2_m, bn2_v, fc3_W, fc3_b, out);
}

// Round 11
// 282.645 us; speedup vs baseline: 3.1046x; 1.1308x over previous
//
#include <hip/hip_runtime.h>

namespace {

constexpr int BB = 2048;   // batch
constexpr int TT = 256;    // time steps
constexpr float L2E = 1.4426950408889634f;  // log2(e)

typedef __attribute__((ext_vector_type(8))) short bf8;          // 8 bf16 (4 VGPR)
typedef __attribute__((ext_vector_type(4))) float f4;           // MFMA acc
typedef __attribute__((ext_vector_type(2))) unsigned int u32x2;

#define MFMA16(a, b, c) __builtin_amdgcn_mfma_f32_16x16x32_bf16((a), (b), (c), 0, 0, 0)

__device__ __forceinline__ unsigned short f2bf_rne(float f) {
  unsigned int x = __float_as_uint(f);
  return (unsigned short)((x + 0x7fffu + ((x >> 16) & 1u)) >> 16);
}
__device__ __forceinline__ void mk_hilo(float v, short& hi, short& lo) {
  unsigned int u = __float_as_uint(v);
  hi = (short)(u >> 16);
  float r = v - __uint_as_float(u & 0xffff0000u);
  lo = (short)(__float_as_uint(r) >> 16);
}

// ACQUIRE poll of an LDS counter (wave-uniform address). Tight spin.
__device__ __forceinline__ void waitq(const unsigned* c, unsigned tgt) {
  while (__hip_atomic_load(c, __ATOMIC_ACQUIRE, __HIP_MEMORY_SCOPE_WORKGROUP) < tgt) {}
}

// ============ all 4 GRU layers, free-running pipelined in one block ============
// 1024 threads = 16 waves = 4 quads; quad g = layer g. Sync via LDS sum-counters.
// h-state ring of 4 slots per layer, fragment-major [u>>3][n][u&7] (conflict-free
// b128 reads). Ring serves both self h-feedback (slot t&3) and next layer's x
// (slot (t+1)&3). Gates pre-scaled by log2e (R,Z) / 2log2e (N) -> raw v_exp_f32.
// R11: x-path (producer wait + x-MFMAs) hoisted BEFORE the peer wait so it
// overlaps peers finishing step t-1; backpressure poll sits under the h-MFMA
// shadow; R/Z share one reciprocal (5 trans/pair instead of 6).
__global__ __launch_bounds__(1024, 4) void gru_all(
    const float* __restrict__ xs, const float* __restrict__ xp,
    const float* __restrict__ W0s, const float* __restrict__ W0p,
    const float* __restrict__ Wihs, const float* __restrict__ Wihp,  // [3][192][64]
    const float* __restrict__ Whhs, const float* __restrict__ Whhp,  // [4][192][64]
    const float* __restrict__ bihs, const float* __restrict__ bihp,  // [4][192]
    const float* __restrict__ bhhs, const float* __restrict__ bhhp,
    float* __restrict__ hlast) {
  const int tid = threadIdx.x;
  const int Wv = tid >> 6, lane = tid & 63;
  const int g = Wv >> 2, w = Wv & 3;      // quad (=layer), wave-in-quad
  const int n15 = lane & 15, q = lane >> 4;
  const int blk = blockIdx.x, stack = blk >> 7;
  const int b0 = (blk & 127) * 16;

  const float* Wh = (stack ? Whhp : Whhs) + (size_t)g * 192 * 64;
  const float* bi = (stack ? bihp : bihs) + g * 192;
  const float* bh = (stack ? bhhp : bhhs) + g * 192;
  const float* Wx = (stack ? Wihp : Wihs) + (size_t)(g - 1) * 192 * 64;  // g>=1

  // [g][slot][frag=u>>3][n][elem=u&7]
  __shared__ unsigned short hb[4][4][8][16][8];
  __shared__ unsigned qdone[4];

  for (int e = tid; e < 4 * 4 * 8 * 16 * 8; e += 1024)
    ((unsigned short*)hb)[e] = 0;
  if (tid < 4) qdone[tid] = 0;
  __syncthreads();  // only barrier in the kernel

  const int mrow = 16 * w + n15;   // A-frag row; wave w owns Mtiles {w, w+4, w+8}
  const int mu = 16 * w + 4 * q;   // C-layout unit base for this lane's 4 regs
  const int fr_w = 2 * w + (q >> 1);  // write frag row
  const int eo_w = (q & 1) * 4;       // write elem offset

  // per-gate pre-scale: R,Z by log2e; N by 2*log2e
  const float gsc[3] = {L2E, L2E, 2.f * L2E};

  // ---- Wh fragments: rne bf16 of (scale * W) ----
  bf8 whh_[3][2];
  #pragma unroll
  for (int i = 0; i < 3; ++i) {
    #pragma unroll
    for (int kt = 0; kt < 2; ++kt) {
      const float* ph_ = Wh + (size_t)(i * 64 + mrow) * 64 + kt * 32 + q * 8;
      f4 ha = *(const f4*)ph_, hc = *(const f4*)(ph_ + 4);
      bf8 h2;
      #pragma unroll
      for (int j = 0; j < 8; ++j)
        h2[j] = (short)f2bf_rne(gsc[i] * ((j < 4) ? ha[j] : hc[j - 4]));
      whh_[i][kt] = h2;
    }
  }
  // ---- Wx fragments ----
  bf8 wxh_[3][2];
  if (g >= 1) {
    #pragma unroll
    for (int i = 0; i < 3; ++i) {
      #pragma unroll
      for (int kt = 0; kt < 2; ++kt) {
        const float* px_ = Wx + (size_t)(i * 64 + mrow) * 64 + kt * 32 + q * 8;
        f4 xa = *(const f4*)px_, xc = *(const f4*)(px_ + 4);
        bf8 h1;
        #pragma unroll
        for (int j = 0; j < 8; ++j)
          h1[j] = (short)f2bf_rne(gsc[i] * ((j < 4) ? xa[j] : xc[j - 4]));
        wxh_[i][kt] = h1;
      }
    }
  } else {
    // layer 0: scaled W0 trunc-hi/lo packed in one K=32 frag (see R6 comment).
    const float* W0 = stack ? W0p : W0s;
    #pragma unroll
    for (int i = 0; i < 3; ++i) {
      bf8 a;
      #pragma unroll
      for (int j = 0; j < 8; ++j) a[j] = 0;
      if (q == 0) {
        if (stack) {
          #pragma unroll
          for (int d = 0; d < 4; ++d) {
            short hi, lo;
            mk_hilo(gsc[i] * W0[(size_t)(i * 64 + mrow) * 4 + d], hi, lo);
            a[d] = hi; a[4 + d] = lo;
          }
        } else {
          short hi, lo; mk_hilo(gsc[i] * W0[i * 64 + mrow], hi, lo);
          a[0] = hi; a[1] = hi; a[4] = lo; a[5] = lo;
        }
      }
      wxh_[i][0] = a; wxh_[i][1] = a;
    }
  }

  f4 bR, bZ, bNx, bNh;
  #pragma unroll
  for (int r = 0; r < 4; ++r) {
    bR[r]  = L2E * (bi[mu + r] + bh[mu + r]);
    bZ[r]  = L2E * (bi[64 + mu + r] + bh[64 + mu + r]);
    bNx[r] = 2.f * L2E * bi[128 + mu + r];
    bNh[r] = 2.f * L2E * bh[128 + mu + r];
  }
  f4 h = {0.f, 0.f, 0.f, 0.f};

  // layer-0 per-lane x prefetch (batch row b0+n15)
  const size_t xrow = (size_t)(b0 + n15);
  float px0 = 0.f, px1 = 0.f, px2 = 0.f, px3 = 0.f;
  if (g == 0) {
    if (stack) { f4 t4 = *(const f4*)(xp + xrow * TT * 4); px0 = t4[0]; px1 = t4[1]; px2 = t4[2]; px3 = t4[3]; }
    else       { px0 = xs[xrow * TT]; }
  }

// One timestep; S is a compile-time ring-slot literal. Order: x-path first
// (producer usually ahead -> overlaps peers finishing), then peer sync + h.
#define GRU_BODY(S)                                                            \
  {                                                                            \
    constexpr int SW = (S + 1) & 3;                                            \
    f4 aR = bR, aZ = bZ, aNx = bNx, aNh = bNh;                                 \
    if (g == 0) {                                                              \
      bf8 xq;                                                                  \
      _Pragma("unroll") for (int j = 0; j < 8; ++j) xq[j] = 0;                 \
      if (q == 0) {                                                            \
        if (stack) {                                                           \
          short a0 = (short)f2bf_rne(px0), a1 = (short)f2bf_rne(px1);          \
          short a2 = (short)f2bf_rne(px2), a3 = (short)f2bf_rne(px3);          \
          xq[0] = a0; xq[1] = a1; xq[2] = a2; xq[3] = a3;                      \
          xq[4] = a0; xq[5] = a1; xq[6] = a2; xq[7] = a3;                      \
        } else {                                                               \
          unsigned short xh = f2bf_rne(px0);                                   \
          float xf = __uint_as_float((unsigned)xh << 16);                      \
          unsigned short xl = f2bf_rne(px0 - xf);                              \
          xq[0] = (short)xh; xq[1] = (short)xl;                                \
          xq[4] = (short)xh; xq[5] = (short)xl;                                \
        }                                                                      \
      }                                                                        \
      __builtin_amdgcn_s_setprio(1);                                           \
      aR  = MFMA16(wxh_[0][0], xq, aR);                                        \
      aZ  = MFMA16(wxh_[1][0], xq, aZ);                                        \
      aNx = MFMA16(wxh_[2][0], xq, aNx);                                       \
      __builtin_amdgcn_s_setprio(0);                                           \
      if (tc + 1 < TT) {                                                       \
        if (stack) { f4 t4 = *(const f4*)(xp + (xrow * TT + tc + 1) * 4);      \
                     px0 = t4[0]; px1 = t4[1]; px2 = t4[2]; px3 = t4[3]; }     \
        else       { px0 = xs[xrow * TT + tc + 1]; }                           \
      }                                                                        \
    } else {                                                                   \
      waitq(&qdone[g - 1], 4u * (unsigned)(tc + 1));                           \
      bf8 xc0 = *(const bf8*)&hb[g - 1][SW][q][n15][0];                        \
      bf8 xc1 = *(const bf8*)&hb[g - 1][SW][4 + q][n15][0];                    \
      __builtin_amdgcn_s_setprio(1);                                           \
      aR  = MFMA16(wxh_[0][0], xc0, aR);  aR  = MFMA16(wxh_[0][1], xc1, aR);   \
      aZ  = MFMA16(wxh_[1][0], xc0, aZ);  aZ  = MFMA16(wxh_[1][1], xc1, aZ);   \
      aNx = MFMA16(wxh_[2][0], xc0, aNx); aNx = MFMA16(wxh_[2][1], xc1, aNx);  \
      __builtin_amdgcn_s_setprio(0);                                           \
    }                                                                          \
    waitq(&qdone[g], 4u * (unsigned)tc);                                       \
    bf8 hh0 = *(const bf8*)&hb[g][S][q][n15][0];                               \
    bf8 hh1 = *(const bf8*)&hb[g][S][4 + q][n15][0];                           \
    __builtin_amdgcn_s_setprio(1);                                             \
    aR  = MFMA16(whh_[0][0], hh0, aR);  aR  = MFMA16(whh_[0][1], hh1, aR);     \
    aZ  = MFMA16(whh_[1][0], hh0, aZ);  aZ  = MFMA16(whh_[1][1], hh1, aZ);     \
    aNh = MFMA16(whh_[2][0], hh0, aNh); aNh = MFMA16(whh_[2][1], hh1, aNh);    \
    __builtin_amdgcn_s_setprio(0);                                             \
    if (g < 3 && tc >= 4) waitq(&qdone[g + 1], 4u * (unsigned)(tc - 3));       \
    _Pragma("unroll") for (int r = 0; r < 4; ++r) {                            \
      float eR = __builtin_amdgcn_exp2f(-aR[r]);                               \
      float eZ = __builtin_amdgcn_exp2f(-aZ[r]);                               \
      float dR = 1.f + eR, dZ = 1.f + eZ;                                      \
      float qq = __builtin_amdgcn_rcpf(dR * dZ);                               \
      float rr = dZ * qq;   /* = 1/dR = sigmoid(aR) */                         \
      float zz = dR * qq;   /* = 1/dZ = sigmoid(aZ) */                         \
      float eN = __builtin_amdgcn_exp2f(aNx[r] + rr * aNh[r]);                 \
      float nn = 1.f - 2.f * __builtin_amdgcn_rcpf(eN + 1.f);                  \
      h[r] = nn + zz * (h[r] - nn);                                            \
    }                                                                          \
    unsigned p01, p23;                                                         \
    asm("v_cvt_pk_bf16_f32 %0, %1, %2" : "=v"(p01) : "v"(h[0]), "v"(h[1]));   \
    asm("v_cvt_pk_bf16_f32 %0, %1, %2" : "=v"(p23) : "v"(h[2]), "v"(h[3]));   \
    u32x2 hiw = {p01, p23};                                                    \
    *(u32x2*)&hb[g][SW][fr_w][n15][eo_w] = hiw;                                \
    if (g == 3 && tc == TT - 1)                                                \
      *(f4*)&hlast[((size_t)stack * BB + b0 + n15) * 64 + mu] = h;             \
    if (lane == 0)                                                             \
      __hip_atomic_fetch_add(&qdone[g], 1u, __ATOMIC_RELEASE,                  \
                             __HIP_MEMORY_SCOPE_WORKGROUP);                    \
  }

  for (int t = 0; t < TT; t += 4) {
    { const int tc = t;     GRU_BODY(0) }
    { const int tc = t + 1; GRU_BODY(1) }
    { const int tc = t + 2; GRU_BODY(2) }
    { const int tc = t + 3; GRU_BODY(3) }
  }
#undef GRU_BODY
}

// ---------------- FC head ----------------
__global__ __launch_bounds__(128) void head(
    const float* __restrict__ hlast,
    const float* __restrict__ W1, const float* __restrict__ b1,
    const float* __restrict__ g1, const float* __restrict__ be1,
    const float* __restrict__ m1, const float* __restrict__ v1,
    const float* __restrict__ W2, const float* __restrict__ b2,
    const float* __restrict__ g2, const float* __restrict__ be2,
    const float* __restrict__ m2, const float* __restrict__ v2,
    const float* __restrict__ W3, const float* __restrict__ b3,
    float* __restrict__ out) {
  const int b = blockIdx.x;
  const int j = threadIdx.x;
  __shared__ float xin[128];
  __shared__ float y1[128];
  __shared__ float y2[128];
  xin[j] = (j < 64) ? hlast[(size_t)b * 64 + j]
                    : hlast[(size_t)BB * 64 + (size_t)b * 64 + (j - 64)];
  __syncthreads();
  float acc = b1[j];
  #pragma unroll 8
  for (int k = 0; k < 128; ++k) acc = fmaf(W1[j * 128 + k], xin[k], acc);
  float sc = g1[j] * rsqrtf(v1[j] + 1e-5f);
  y1[j] = fmaxf(0.f, (acc - m1[j]) * sc + be1[j]);
  __syncthreads();
  acc = b2[j];
  #pragma unroll 8
  for (int k = 0; k < 128; ++k) acc = fmaf(W2[j * 128 + k], y1[k], acc);
  sc = g2[j] * rsqrtf(v2[j] + 1e-5f);
  y2[j] = fmaxf(0.f, (acc - m2[j]) * sc + be2[j]);
  __syncthreads();
  if (j < 2) {
    float a = b3[j];
    #pragma unroll 8
    for (int k = 0; k < 128; ++k) a = fmaf(W3[j * 128 + k], y2[k], a);
    out[(size_t)b * 2 + j] = a;
  }
}

}  // namespace

extern "C" void kernel_launch(void* const* d_in, const int* in_sizes, int n_in,
                              void* d_out, int out_size, void* d_ws, size_t ws_size,
                              hipStream_t stream) {
  (void)in_sizes; (void)n_in; (void)out_size; (void)ws_size;
  const float* sent   = (const float*)d_in[0];
  const float* price  = (const float*)d_in[1];
  const float* s_Wih0 = (const float*)d_in[2];
  const float* s_Wih  = (const float*)d_in[3];
  const float* s_Whh  = (const float*)d_in[4];
  const float* s_bih  = (const float*)d_in[5];
  const float* s_bhh  = (const float*)d_in[6];
  const float* p_Wih0 = (const float*)d_in[7];
  const float* p_Wih  = (const float*)d_in[8];
  const float* p_Whh  = (const float*)d_in[9];
  const float* p_bih  = (const float*)d_in[10];
  const float* p_bhh  = (const float*)d_in[11];
  const float* fc1_W  = (const float*)d_in[12];
  const float* fc1_b  = (const float*)d_in[13];
  const float* bn1_g  = (const float*)d_in[14];
  const float* bn1_b  = (const float*)d_in[15];
  const float* bn1_m  = (const float*)d_in[16];
  const float* bn1_v  = (const float*)d_in[17];
  const float* fc2_W  = (const float*)d_in[18];
  const float* fc2_b  = (const float*)d_in[19];
  const float* bn2_g  = (const float*)d_in[20];
  const float* bn2_b  = (const float*)d_in[21];
  const float* bn2_m  = (const float*)d_in[22];
  const float* bn2_v  = (const float*)d_in[23];
  const float* fc3_W  = (const float*)d_in[24];
  const float* fc3_b  = (const float*)d_in[25];
  float* out = (float*)d_out;

  float* hlast = (float*)d_ws;  // [2, B, 64] f32

  gru_all<<<dim3(256), dim3(1024), 0, stream>>>(
      sent, price, s_Wih0, p_Wih0, s_Wih, p_Wih, s_Whh, p_Whh,
      s_bih, p_bih, s_bhh, p_bhh, hlast);

  head<<<dim3(BB), dim3(128), 0, stream>>>(
      hlast, fc1_W, fc1_b, bn1_g, bn1_b, bn1_m, bn1_v,
      fc2_W, fc2_b, bn2_g, bn2_b, bn2_m, bn2_v, fc3_W, fc3_b, out);
}